// Round 18
// baseline (529.748 us; speedup 1.0000x reference)
//
#include <hip/hip_runtime.h>
#include <hip/hip_bf16.h>
#include <math.h>

typedef __hip_bfloat16 bf16;
typedef __attribute__((ext_vector_type(8))) short bf16x8;
typedef __attribute__((ext_vector_type(4))) float f32x4;

static constexpr int B_ = 8, C_ = 128, H_ = 128, W_ = 128;
static constexpr int N_ = H_ * W_;          // 16384
static constexpr int NWIN = 648;            // B * 9 * 9

__device__ __forceinline__ float b2f(bf16 v) { return __bfloat162float(v); }
__device__ __forceinline__ bf16 f2b(float v) { return __float2bfloat16(v); }

// erf-free exact-GELU: A&S 7.1.26 rational erf approx (|err|<=1.5e-7), pure FMA + v_exp.
__device__ __forceinline__ float gelu_f(float x) {
    float xs = x * 0.70710678118654752f;
    float ax = fabsf(xs);
    float t = 1.0f / fmaf(0.3275911f, ax, 1.0f);
    float poly = t * fmaf(t, fmaf(t, fmaf(t, fmaf(t, 1.061405429f, -1.453152027f), 1.421413741f), -0.284496736f), 0.254829592f);
    float erf_ax = fmaf(-poly, __expf(-ax * ax), 1.0f);
    float erfv = copysignf(erf_ax, xs);
    return 0.5f * x * (1.0f + erfv);
}

// 12-wide row extraction from padded plane tile (row bytes: [0,16) left pad, [16,272) cols, [272,288) right pad)
__device__ __forceinline__ void load_row12(const char* tile, int a, int wg, float* dst) {
    int base = a * 288 + wg * 16;
    union { uint4 u; bf16 hh[8]; } c0, c1, c2;
    c0.u = *(const uint4*)(tile + base);
    c1.u = *(const uint4*)(tile + base + 16);
    c2.u = *(const uint4*)(tile + base + 32);
    dst[0] = b2f(c0.hh[6]); dst[1] = b2f(c0.hh[7]);
    #pragma unroll
    for (int j = 0; j < 8; ++j) dst[2 + j] = b2f(c1.hh[j]);
    dst[10] = b2f(c2.hh[0]); dst[11] = b2f(c2.hh[1]);
}

// ---------------- K0: all weight preps merged (one-off) ----------------
__global__ __launch_bounds__(256) void k_wprep(const float* __restrict__ projw, const float* __restrict__ qkvw,
                                               const float* __restrict__ gatew, const float* __restrict__ w1,
                                               const float* __restrict__ w2, const float* __restrict__ pww,
                                               bf16* __restrict__ wt, bf16* __restrict__ wqkv,
                                               bf16* __restrict__ wt1, bf16* __restrict__ wt2,
                                               bf16* __restrict__ wpw) {
    int idx = blockIdx.x * 256 + threadIdx.x;    // 163840
    if (idx < 16384) {
        int o = idx >> 7, c = idx & 127;
        wt[idx] = f2b(projw[c * 128 + o]);
    } else if (idx < 81920) {
        int i = idx - 16384; int o = i >> 7, c = i & 127;
        wqkv[i] = f2b((o < 384) ? qkvw[c * 384 + o] : gatew[c * 128 + (o - 384)]);
    } else if (idx < 114688) {
        int i = idx - 81920; int o = i >> 7, c = i & 127;
        wt1[i] = f2b(w1[c * 256 + o]);
    } else if (idx < 147456) {
        int i = idx - 114688; int o = i >> 8, c = i & 255;
        wt2[i] = f2b(w2[c * 128 + o]);
    } else {
        int i = idx - 147456;
        wpw[i] = f2b(pww[i]);
    }
}

// ---------------- K1: fused 2x2-pool + bilinear-up + hf = x - up (bf16 out) ----------------
__global__ __launch_bounds__(256) void k_hf2(const float* __restrict__ x, bf16* __restrict__ hf) {
    __shared__ float lowt[10][64];
    int tid = threadIdx.x;
    int bid = blockIdx.x;                       // 8192 = 8b * 128c * 8ht
    int ht = bid & 7, c = (bid >> 3) & 127, b = bid >> 10;
    const float* xp = x + (size_t)(b * C_ + c) * N_;
    int h0 = ht * 16;
    int lo0 = (h0 >> 1) - 1;
    for (int e = tid; e < 640; e += 256) {
        int lr = e >> 6, jc = e & 63;
        int j = lo0 + lr; j = j < 0 ? 0 : (j > 63 ? 63 : j);
        const float* pr = xp + (2 * j) * W_ + 2 * jc;
        lowt[lr][jc] = (pr[0] + pr[1] + pr[W_] + pr[W_ + 1]) * 0.25f;
    }
    __syncthreads();
    int hl = tid >> 4, wg = tid & 15;
    int h = h0 + hl;
    int jh = h >> 1;
    int j0, j1; float wh0, wh1;
    if (h & 1) { j0 = jh; j1 = jh + 1 > 63 ? 63 : jh + 1; wh0 = 0.75f; wh1 = 0.25f; }
    else       { j0 = jh - 1 < 0 ? 0 : jh - 1; j1 = jh;   wh0 = 0.25f; wh1 = 0.75f; }
    int l0 = j0 - lo0, l1 = j1 - lo0;
    float4 xa = *(const float4*)(xp + h * W_ + wg * 8);
    float4 xb = *(const float4*)(xp + h * W_ + wg * 8 + 4);
    float xv[8] = {xa.x, xa.y, xa.z, xa.w, xb.x, xb.y, xb.z, xb.w};
    union { bf16 hh[8]; uint4 u; } outv;
    #pragma unroll
    for (int k2 = 0; k2 < 8; ++k2) {
        int w = wg * 8 + k2;
        int jw = w >> 1;
        int w0, w1; float ww0, ww1;
        if (w & 1) { w0 = jw; w1 = jw + 1 > 63 ? 63 : jw + 1; ww0 = 0.75f; ww1 = 0.25f; }
        else       { w0 = jw - 1 < 0 ? 0 : jw - 1; w1 = jw;   ww0 = 0.25f; ww1 = 0.75f; }
        float up = wh0 * (ww0 * lowt[l0][w0] + ww1 * lowt[l0][w1])
                 + wh1 * (ww0 * lowt[l1][w0] + ww1 * lowt[l1][w1]);
        outv.hh[k2] = f2b(xv[k2] - up);
    }
    *(uint4*)(hf + (size_t)(b * C_ + c) * N_ + h * W_ + wg * 8) = outv.u;
}

// ---------------- K2: sgate (fp32 out) ----------------
__global__ __launch_bounds__(256) void k_sgate(const bf16* __restrict__ hf, const float* __restrict__ gw,
                                               const float* __restrict__ gb, float* __restrict__ sg) {
    int idx = blockIdx.x * 256 + threadIdx.x;       // 131072
    int n = idx & (N_ - 1); int b = idx >> 14;
    const bf16* p = hf + (size_t)b * C_ * N_ + n;
    float s = 0.f;
    for (int c = 0; c < C_; ++c) s += gw[c] * fabsf(b2f(p[(size_t)c * N_]));
    s += gb[0];
    sg[idx] = 1.0f / (1.0f + __expf(-s));
}

// ---------------- K3: g = gelu(dwconv3x3 dil2) full-plane LDS (bf16) ----------------
__global__ __launch_bounds__(256) void k_dw3p(const bf16* __restrict__ hf, const float* __restrict__ wdw,
                                              bf16* __restrict__ g) {
    __shared__ __align__(16) char tile[38016];     // 132 rows x 288B (8-col zero pads each side)
    int tid = threadIdx.x;
    int bid = blockIdx.x;                          // 1024 = 8b * 128c
    int ch = bid & 127, b = bid >> 7;
    const bf16* p = hf + (size_t)(b * C_ + ch) * N_;
    for (int e = tid; e < 2376; e += 256) *(uint4*)(tile + e * 16) = (uint4){0, 0, 0, 0};
    __syncthreads();
    for (int e = tid; e < 2048; e += 256) {
        int gr = e >> 4, slot = e & 15;
        uint4 val = *(const uint4*)(p + gr * 128 + slot * 8);
        *(uint4*)(tile + (gr + 2) * 288 + 16 + slot * 16) = val;
    }
    float kw[9];
    #pragma unroll
    for (int j = 0; j < 9; ++j) kw[j] = wdw[ch * 9 + j];
    __syncthreads();
    int hg = tid >> 4, wg = tid & 15;
    int h0 = hg * 8;
    float ring[5][12];
    #pragma unroll
    for (int j = 0; j < 4; ++j) load_row12(tile, h0 + j, wg, ring[j]);
    bf16* op = g + (size_t)(b * C_ + ch) * N_;
    #pragma unroll
    for (int rr = 0; rr < 8; ++rr) {
        load_row12(tile, h0 + rr + 4, wg, ring[(rr + 4) % 5]);
        float acc[8] = {};
        #pragma unroll
        for (int ky = 0; ky < 3; ++ky) {
            const float* e = ring[(rr + 2 * ky) % 5];
            #pragma unroll
            for (int ow = 0; ow < 8; ++ow) {
                acc[ow] = fmaf(kw[ky * 3 + 0], e[ow], acc[ow]);
                acc[ow] = fmaf(kw[ky * 3 + 1], e[ow + 2], acc[ow]);
                acc[ow] = fmaf(kw[ky * 3 + 2], e[ow + 4], acc[ow]);
            }
        }
        union { bf16 h[8]; uint4 u; } outv;
        #pragma unroll
        for (int ow = 0; ow < 8; ++ow) outv.h[ow] = f2b(gelu_f(acc[ow]));
        *(uint4*)(op + (h0 + rr) * 128 + wg * 8) = outv.u;
    }
}

// ---------------- K4: pw MFMA GEMM + LTH epilogue -> x1 (bf16) ----------------
__global__ __launch_bounds__(256) void k_pw_mfma(const bf16* __restrict__ g, const bf16* __restrict__ wpw,
                                                 const float* __restrict__ pwb, const float* __restrict__ x,
                                                 const float* __restrict__ scale, const float* __restrict__ sg,
                                                 bf16* __restrict__ x1) {
    __shared__ __align__(16) char lds[49152];   // [0,16K): A tile; [16K,48K): W
    int tid = threadIdx.x;
    int lane = tid & 63, w = tid >> 6;
    int l15 = lane & 15, lhi = lane >> 4;
    int gtok = blockIdx.x * 64; int b = gtok >> 14; int nb = gtok & (N_ - 1);
    char* wch = lds + 16384;
    for (int e = tid; e < 8192; e += 256) {
        int c = e >> 6, i = e & 63;
        bf16 val = g[(size_t)(b * C_ + c) * N_ + nb + i];
        *(bf16*)(lds + i * 256 + ((2 * c) ^ ((i & 7) << 4))) = val;
    }
    for (int e = tid; e < 2048; e += 256) {
        int row = e >> 4, slot = e & 15;
        uint4 val = *(const uint4*)((const char*)wpw + row * 256 + slot * 16);
        *(uint4*)(wch + row * 256 + ((slot * 16) ^ ((row & 7) << 4))) = val;
    }
    __syncthreads();
    bf16x8 afr[4];
    {
        int row = w * 16 + l15;
        #pragma unroll
        for (int cc = 0; cc < 4; ++cc) {
            int cbyt = cc * 64 + lhi * 16;
            afr[cc] = *(const bf16x8*)(lds + row * 256 + (cbyt ^ ((row & 7) << 4)));
        }
    }
    f32x4 acc[8];
    #pragma unroll
    for (int t = 0; t < 8; ++t) acc[t] = (f32x4){0.f, 0.f, 0.f, 0.f};
    #pragma unroll
    for (int ot = 0; ot < 8; ++ot) {
        int row = ot * 16 + l15;
        #pragma unroll
        for (int cc = 0; cc < 4; ++cc) {
            int cbyt = cc * 64 + lhi * 16;
            bf16x8 bfr = *(const bf16x8*)(wch + row * 256 + (cbyt ^ ((row & 7) << 4)));
            acc[ot] = __builtin_amdgcn_mfma_f32_16x16x32_bf16(afr[cc], bfr, acc[ot], 0, 0, 0);
        }
    }
    int n0 = nb + w * 16 + lhi * 4;
    float4 sg4 = *(const float4*)&sg[b * N_ + n0];
    #pragma unroll
    for (int ot = 0; ot < 8; ++ot) {
        int o = ot * 16 + l15;
        size_t obase = (size_t)(b * C_ + o) * N_ + n0;
        float4 x4 = *(const float4*)&x[obase];
        float sc = scale[o], bi = pwb[o];
        union { bf16 h[4]; uint2 u; } t4;
        t4.h[0] = f2b(x4.x + sc * (acc[ot][0] + bi) * sg4.x);
        t4.h[1] = f2b(x4.y + sc * (acc[ot][1] + bi) * sg4.y);
        t4.h[2] = f2b(x4.z + sc * (acc[ot][2] + bi) * sg4.z);
        t4.h[3] = f2b(x4.w + sc * (acc[ot][3] + bi) * sg4.w);
        *(uint2*)(x1 + obase) = t4.u;
    }
}

// ---------------- K5: LN1 + qkv/gate MFMA GEMM -> q,k,z [tok][c]; v [c][tok] ----------------
// R18: R14 dataflow (proven deterministic) + LDS-repacked q/k/z epilogue: acc written to the
// dead y-tile region as [tok][o] (272B stride), then 4 coalesced uint4 global stores/thread.
// Fixes 166MB WRITE_SIZE (4x amplification from scalar [tok][c] stores).
__global__ __launch_bounds__(256) void k_qkv_mfma(const bf16* __restrict__ x1, const float* __restrict__ lng,
                                                  const float* __restrict__ lnb, const bf16* __restrict__ wall,
                                                  const float* __restrict__ gateb,
                                                  bf16* __restrict__ q, bf16* __restrict__ k,
                                                  bf16* __restrict__ v, bf16* __restrict__ z) {
    __shared__ __align__(16) char lds[49664];   // [0,16K): y bf16 swizzled (dead after afr hoist -> repack buf);
                                                // [16K,...): xf fp32 [128][65] -> w chunk
    __shared__ float red2[8][64];
    __shared__ float mu_l[64], rs_l[64];
    int tid = threadIdx.x;
    int lane = tid & 63, w = tid >> 6;
    int l15 = lane & 15, lhi = lane >> 4;
    int win = blockIdx.x >> 2; int qbase = (blockIdx.x & 3) * 64;
    int b = win / 81; int r0 = win % 81; int top = (r0 / 9) * 14, left = (r0 % 9) * 14;
    float* xf = (float*)(lds + 16384);           // [128][65] fp32
    char* wchunk = lds + 16384;                  // same region, after xf dies
    for (int e = tid; e < 8192; e += 256) {
        int c = e >> 6, i = e & 63; int tok = qbase + i; int p = tok >> 4, qq = tok & 15;
        xf[c * 65 + i] = b2f(x1[(size_t)(b * C_ + c) * N_ + (top + p) * W_ + (left + qq)]);
    }
    __syncthreads();
    {
        int i = tid & 63, r = tid >> 6;
        float s = 0.f, ss = 0.f;
        for (int cc = r * 32; cc < r * 32 + 32; ++cc) { float vv = xf[cc * 65 + i]; s += vv; ss += vv * vv; }
        red2[r][i] = s; red2[4 + r][i] = ss;
    }
    __syncthreads();
    if (tid < 64) {
        float s = red2[0][tid] + red2[1][tid] + red2[2][tid] + red2[3][tid];
        float ss = red2[4][tid] + red2[5][tid] + red2[6][tid] + red2[7][tid];
        float mu = s * (1.f / 128.f); float var = ss * (1.f / 128.f) - mu * mu;
        mu_l[tid] = mu; rs_l[tid] = rsqrtf(var + 1e-6f);
    }
    __syncthreads();
    {
        int c = tid & 127;
        float g = lng[c], be = lnb[c];
        for (int e = tid; e < 8192; e += 256) {
            int i = e >> 7;
            float val = (xf[c * 65 + i] - mu_l[i]) * rs_l[i] * g + be;
            *(bf16*)(lds + i * 256 + ((2 * c) ^ ((i & 7) << 4))) = f2b(val);
        }
    }
    __syncthreads();
    bf16x8 afr[4];
    {
        int row = w * 16 + l15;
        #pragma unroll
        for (int cc = 0; cc < 4; ++cc) {
            int cbyt = cc * 64 + lhi * 16;
            afr[cc] = *(const bf16x8*)(lds + row * 256 + (cbyt ^ ((row & 7) << 4)));
        }
    }
    __syncthreads();   // afr hoisted by ALL waves; y-tile region now dead -> repack buffer
    for (int pass = 0; pass < 4; ++pass) {
        __syncthreads();
        for (int e = tid; e < 2048; e += 256) {
            int row = e >> 4, slot = e & 15;
            uint4 val = *(const uint4*)((const char*)wall + (size_t)(pass * 128 + row) * 256 + slot * 16);
            *(uint4*)(wchunk + row * 256 + ((slot * 16) ^ ((row & 7) << 4))) = val;
        }
        __syncthreads();
        f32x4 acc[8];
        #pragma unroll
        for (int t = 0; t < 8; ++t) acc[t] = (f32x4){0.f, 0.f, 0.f, 0.f};
        #pragma unroll
        for (int ot = 0; ot < 8; ++ot) {
            int row = ot * 16 + l15;
            #pragma unroll
            for (int cc = 0; cc < 4; ++cc) {
                int cbyt = cc * 64 + lhi * 16;
                bf16x8 bfr = *(const bf16x8*)(wchunk + row * 256 + (cbyt ^ ((row & 7) << 4)));
                acc[ot] = __builtin_amdgcn_mfma_f32_16x16x32_bf16(afr[cc], bfr, acc[ot], 0, 0, 0);
            }
        }
        if (pass != 2) {
            bf16* outp = (pass == 0) ? q : (pass == 1) ? k : z;   // [win][tok][c]
            bool gel = (pass == 3);
            // repack: acc -> lds [tok][o] stride 272B (spills 1KB into consumed wchunk rows 0..3)
            {
                int tokl = w * 16 + lhi * 4;
                #pragma unroll
                for (int ot = 0; ot < 8; ++ot) {
                    int o = ot * 16 + l15;
                    float gb = gel ? gateb[o] : 0.f;
                    #pragma unroll
                    for (int r = 0; r < 4; ++r) {
                        float vv = acc[ot][r];
                        bf16 hv = gel ? f2b(gelu_f(vv + gb)) : f2b(vv);
                        *(bf16*)(lds + (tokl + r) * 272 + o * 2) = hv;
                    }
                }
            }
            __syncthreads();
            // coalesced store: thread = (tok, o-quarter); 4 uint4 each
            {
                int tok = tid >> 2, og = tid & 3;
                bf16* dst = outp + ((size_t)win * 256 + qbase + tok) * 128 + og * 32;
                const char* src = lds + tok * 272 + og * 64;
                #pragma unroll
                for (int j = 0; j < 4; ++j)
                    *(uint4*)(dst + j * 8) = *(const uint4*)(src + j * 16);
            }
        } else {                                  // v: [win][c][tok] (already packed along tok)
            #pragma unroll
            for (int ot = 0; ot < 8; ++ot) {
                int o = ot * 16 + l15;
                union { bf16 h[4]; uint2 u; } t4;
                #pragma unroll
                for (int r = 0; r < 4; ++r) t4.h[r] = f2b(acc[ot][r]);
                *(uint2*)(v + (size_t)win * 32768 + (size_t)o * 256 + qbase + w * 16 + lhi * 4) = t4.u;
            }
        }
    }
}

// ---------------- K6: MFMA attention core: softmax(QK^T*scale)V -> o [win][tok][c] ----------------
// R15 (validated): XCD-aware block map (4 quarters of a window share an XCD -> k/v L2 reuse);
// PV operand swap -> packed uint2 o-stores.
__global__ __launch_bounds__(256) void k_attn_mfma(const bf16* __restrict__ qb, const bf16* __restrict__ kb,
                                                   const bf16* __restrict__ vb, bf16* __restrict__ ob) {
    __shared__ __align__(16) char lds[49152];   // [0,32K): q (16K) then P (32K); [32K,48K): K/V chunk
    int tid = threadIdx.x;
    int lane = tid & 63, w = tid >> 6;
    int l15 = lane & 15, lhi = lane >> 4;
    int xcd = blockIdx.x & 7, ixd = blockIdx.x >> 3;   // 648 windows = 8 XCDs x 81
    int win = xcd * 81 + (ixd >> 2);
    int qbase = (ixd & 3) * 64;
    const bf16* qg = qb + ((size_t)win * 256 + qbase) * 128;   // [64][128]
    const bf16* kg = kb + (size_t)win * 256 * 128;             // [256][128]
    const bf16* vg = vb + (size_t)win * 128 * 256;             // [128][256]
    char* chunk = lds + 32768;
    for (int e = tid; e < 1024; e += 256) {
        int row = e >> 4, slot = e & 15;
        uint4 val = *(const uint4*)((const char*)qg + row * 256 + slot * 16);
        *(uint4*)(lds + row * 256 + ((slot * 16) ^ ((row & 7) << 4))) = val;
    }
    __syncthreads();
    bf16x8 afr[4];
    {
        int row = w * 16 + l15;
        #pragma unroll
        for (int cc = 0; cc < 4; ++cc) {
            int cb = cc * 64 + lhi * 16;
            afr[cc] = *(const bf16x8*)(lds + row * 256 + (cb ^ ((row & 7) << 4)));
        }
    }
    f32x4 acc[16];
    #pragma unroll
    for (int t = 0; t < 16; ++t) acc[t] = (f32x4){0.f, 0.f, 0.f, 0.f};
    for (int kc = 0; kc < 4; ++kc) {
        __syncthreads();
        for (int e = tid; e < 1024; e += 256) {
            int row = e >> 4, slot = e & 15;
            uint4 val = *(const uint4*)((const char*)kg + (size_t)(kc * 64 + row) * 256 + slot * 16);
            *(uint4*)(chunk + row * 256 + ((slot * 16) ^ ((row & 7) << 4))) = val;
        }
        __syncthreads();
        #pragma unroll
        for (int t = 0; t < 4; ++t) {
            int row = t * 16 + l15;
            #pragma unroll
            for (int cc = 0; cc < 4; ++cc) {
                int cb = cc * 64 + lhi * 16;
                bf16x8 bfr = *(const bf16x8*)(chunk + row * 256 + (cb ^ ((row & 7) << 4)));
                acc[kc * 4 + t] = __builtin_amdgcn_mfma_f32_16x16x32_bf16(afr[cc], bfr, acc[kc * 4 + t], 0, 0, 0);
            }
        }
    }
    const float sm_scale = 0.08838834764831845f;   // 128^-0.5
    #pragma unroll
    for (int r = 0; r < 4; ++r) {
        float m = -1e30f;
        #pragma unroll
        for (int t = 0; t < 16; ++t) m = fmaxf(m, acc[t][r]);
        #pragma unroll
        for (int d2 = 1; d2 < 16; d2 <<= 1) m = fmaxf(m, __shfl_xor(m, d2, 64));
        float ssum = 0.f;
        #pragma unroll
        for (int t = 0; t < 16; ++t) { float p = __expf((acc[t][r] - m) * sm_scale); acc[t][r] = p; ssum += p; }
        #pragma unroll
        for (int d2 = 1; d2 < 16; d2 <<= 1) ssum += __shfl_xor(ssum, d2, 64);
        float inv = 1.f / ssum;
        #pragma unroll
        for (int t = 0; t < 16; ++t) acc[t][r] *= inv;
    }
    #pragma unroll
    for (int t = 0; t < 16; ++t) {
        #pragma unroll
        for (int r = 0; r < 4; ++r) {
            int row = w * 16 + lhi * 4 + r;
            int cb = (t * 16 + l15) * 2;
            *(bf16*)(lds + row * 512 + (cb ^ ((row & 7) << 4))) = f2b(acc[t][r]);
        }
    }
    f32x4 oacc[8];
    #pragma unroll
    for (int t = 0; t < 8; ++t) oacc[t] = (f32x4){0.f, 0.f, 0.f, 0.f};
    for (int vc = 0; vc < 4; ++vc) {
        __syncthreads();
        for (int e = tid; e < 1024; e += 256) {
            int row = e >> 3, slot = e & 7;
            uint4 val = *(const uint4*)((const char*)vg + (size_t)row * 512 + vc * 128 + slot * 16);
            *(uint4*)(chunk + row * 128 + ((slot * 16) ^ ((row & 7) << 4))) = val;
        }
        __syncthreads();
        #pragma unroll
        for (int jc = 0; jc < 2; ++jc) {
            int prow = w * 16 + l15;
            int pcb = vc * 128 + jc * 64 + lhi * 16;
            bf16x8 ap = *(const bf16x8*)(lds + prow * 512 + (pcb ^ ((prow & 7) << 4)));
            #pragma unroll
            for (int ct = 0; ct < 8; ++ct) {
                int vrow = ct * 16 + l15;
                int vcb = jc * 64 + lhi * 16;
                bf16x8 bv = *(const bf16x8*)(chunk + vrow * 128 + (vcb ^ ((vrow & 7) << 4)));
                // swapped: D[c][tok] -> c contiguous per thread
                oacc[ct] = __builtin_amdgcn_mfma_f32_16x16x32_bf16(bv, ap, oacc[ct], 0, 0, 0);
            }
        }
    }
    bf16* og = ob + ((size_t)win * 256 + qbase) * 128;
    {
        int tok = w * 16 + l15;
        #pragma unroll
        for (int ct = 0; ct < 8; ++ct) {
            int c4 = ct * 16 + lhi * 4;
            union { bf16 h[4]; uint2 u; } t4;
            #pragma unroll
            for (int r = 0; r < 4; ++r) t4.h[r] = f2b(oacc[ct][r]);
            *(uint2*)(og + tok * 128 + c4) = t4.u;
        }
    }
}

// ---------------- K7: u = (o + PE(q)) * z, in place over o [win][tok][c] (elementwise) ----------------
__global__ __launch_bounds__(256) void k_peg(bf16* __restrict__ ob, const bf16* __restrict__ qb,
                                             const bf16* __restrict__ zb,
                                             const float* __restrict__ pew, const float* __restrict__ peb) {
    __shared__ float pw_lds[1152];
    __shared__ float pb_lds[128];
    int tid = threadIdx.x;
    for (int e = tid; e < 1152; e += 256) pw_lds[e] = pew[e];
    if (tid < 128) pb_lds[tid] = peb[tid];
    __syncthreads();
    int g = blockIdx.x * 256 + tid;          // 2,654,208 threads
    int c8 = g & 15, tok = (g >> 4) & 255, win = g >> 12;
    int cb = c8 * 8;
    int pp = tok >> 4, qq = tok & 15;
    size_t base = ((size_t)win * 256 + tok) * 128 + cb;
    float pv[8];
    #pragma unroll
    for (int cc = 0; cc < 8; ++cc) pv[cc] = pb_lds[cb + cc];
    #pragma unroll
    for (int ky = 0; ky < 3; ++ky) {
        int py = pp + ky - 1; if ((unsigned)py >= 16u) continue;
        #pragma unroll
        for (int kx = 0; kx < 3; ++kx) {
            int qx = qq + kx - 1; if ((unsigned)qx >= 16u) continue;
            union { uint4 u; bf16 h[8]; } qu;
            qu.u = *(const uint4*)(qb + ((size_t)win * 256 + py * 16 + qx) * 128 + cb);
            #pragma unroll
            for (int cc = 0; cc < 8; ++cc)
                pv[cc] += pw_lds[(cb + cc) * 9 + ky * 3 + kx] * b2f(qu.h[cc]);
        }
    }
    union { uint4 u; bf16 h[8]; } ou, zu, ru;
    ou.u = *(const uint4*)(ob + base);
    zu.u = *(const uint4*)(zb + base);
    #pragma unroll
    for (int cc = 0; cc < 8; ++cc)
        ru.h[cc] = f2b((b2f(ou.h[cc]) + pv[cc]) * b2f(zu.h[cc]));
    *(uint4*)(ob + base) = ru.u;
}

// ---------------- K8: proj MFMA GEMM + crop residual -> t2 [win][c][tok] ----------------
__global__ __launch_bounds__(256) void k_proj(const bf16* __restrict__ ub, const bf16* __restrict__ wt,
                                              const bf16* __restrict__ x1, bf16* __restrict__ t2) {
    __shared__ __align__(16) char lds[49152];   // [0,16K): u tile; [16K,48K): wt tile
    int tid = threadIdx.x;
    int lane = tid & 63, w = tid >> 6;
    int l15 = lane & 15, lhi = lane >> 4;
    int win = blockIdx.x >> 2, qbase = (blockIdx.x & 3) * 64;
    int b = win / 81; int r0 = win % 81; int top = (r0 / 9) * 14, left = (r0 % 9) * 14;
    const bf16* ug = ub + ((size_t)win * 256 + qbase) * 128;   // [64][128]
    char* wchunk = lds + 16384;
    for (int e = tid; e < 1024; e += 256) {
        int row = e >> 4, slot = e & 15;
        uint4 val = *(const uint4*)((const char*)ug + row * 256 + slot * 16);
        *(uint4*)(lds + row * 256 + ((slot * 16) ^ ((row & 7) << 4))) = val;
    }
    for (int e = tid; e < 2048; e += 256) {
        int row = e >> 4, slot = e & 15;
        uint4 val = *(const uint4*)((const char*)wt + row * 256 + slot * 16);
        *(uint4*)(wchunk + row * 256 + ((slot * 16) ^ ((row & 7) << 4))) = val;
    }
    __syncthreads();
    bf16x8 afr[4];
    {
        int row = w * 16 + l15;
        #pragma unroll
        for (int cc = 0; cc < 4; ++cc) {
            int cbyt = cc * 64 + lhi * 16;
            afr[cc] = *(const bf16x8*)(lds + row * 256 + (cbyt ^ ((row & 7) << 4)));
        }
    }
    f32x4 acc[8];
    #pragma unroll
    for (int t = 0; t < 8; ++t) acc[t] = (f32x4){0.f, 0.f, 0.f, 0.f};
    #pragma unroll
    for (int ot = 0; ot < 8; ++ot) {
        int row = ot * 16 + l15;
        #pragma unroll
        for (int cc = 0; cc < 4; ++cc) {
            int cbyt = cc * 64 + lhi * 16;
            bf16x8 bfr = *(const bf16x8*)(wchunk + row * 256 + (cbyt ^ ((row & 7) << 4)));
            acc[ot] = __builtin_amdgcn_mfma_f32_16x16x32_bf16(afr[cc], bfr, acc[ot], 0, 0, 0);
        }
    }
    int gtok0 = qbase + w * 16 + lhi * 4;
    int p = gtok0 >> 4, qq = gtok0 & 15;       // qq = lhi*4; qq+3 <= 15, row not crossed
    #pragma unroll
    for (int ot = 0; ot < 8; ++ot) {
        int o = ot * 16 + l15;
        const uint* xr32 = (const uint*)(x1 + (size_t)(b * C_ + o) * N_ + (top + p) * W_ + left + qq);
        union { uint u2[2]; bf16 h[4]; } xv;
        xv.u2[0] = xr32[0]; xv.u2[1] = xr32[1];
        union { bf16 h[4]; uint2 u; } t4;
        #pragma unroll
        for (int r = 0; r < 4; ++r) t4.h[r] = f2b(acc[ot][r] + b2f(xv.h[r]));
        *(uint2*)(t2 + (size_t)win * 32768 + (size_t)o * 256 + gtok0) = t4.u;
    }
}

// ---------------- K9: fused fold + LN2 + fc1 MFMA GEMM + gelu -> h1 (bf16), x2 (bf16) ----------------
__global__ __launch_bounds__(256) void k_fc1ln(const bf16* __restrict__ t2, const float* __restrict__ lng,
                                               const float* __restrict__ lnb, const bf16* __restrict__ wt1,
                                               const float* __restrict__ b1, bf16* __restrict__ h1,
                                               bf16* __restrict__ x2w) {
    __shared__ __align__(16) char lds[49664];   // [0,16K): A bf16 swizzled; [16K,...): xf fp32 [128][65] -> w chunk
    __shared__ float red2[8][64];
    __shared__ float mu_l[64], rs_l[64];
    int tid = threadIdx.x;
    int lane = tid & 63, w = tid >> 6;
    int l15 = lane & 15, lhi = lane >> 4;
    int gtok = blockIdx.x * 64; int b = gtok >> 14; int nb = gtok & (N_ - 1);
    int h = nb >> 7, w0 = nb & 127;
    int imin = (h < 16) ? 0 : (h - 2) / 14; int imax = h / 14; if (imax > 8) imax = 8;
    int jmin0 = (w0 < 16) ? 0 : (w0 - 2) / 14;
    int jmax0 = (w0 + 63) / 14; if (jmax0 > 8) jmax0 = 8;
    float* xf = (float*)(lds + 16384);
    char* wch = lds + 16384;
    for (int e = tid; e < 8320; e += 256) xf[e] = 0.f;
    __syncthreads();
    {
        int c = tid >> 1, half = tid & 1;
        for (int ii = imin; ii <= imax; ++ii) {
            int trow = h - ii * 14;
            for (int jj = jmin0; jj <= jmax0; ++jj) {
                int s = jj * 14 - w0 + half * 8;
                if (s >= 0 && s <= 56) {
                    const bf16* tp = t2 + (size_t)((b * 9 + ii) * 9 + jj) * 32768
                                   + (size_t)c * 256 + trow * 16 + half * 8;
                    union { uint4 u; bf16 hh[8]; } qv;
                    qv.u = *(const uint4*)tp;
                    float* xr = xf + c * 65 + s;
                    #pragma unroll
                    for (int k2 = 0; k2 < 8; ++k2) xr[k2] += b2f(qv.hh[k2]);
                }
            }
        }
    }
    __syncthreads();
    for (int e = tid; e < 2048; e += 256) {
        int c = e >> 4, qd = e & 15;
        int i0 = qd * 4;
        union { bf16 hh[4]; uint2 u; } t4;
        #pragma unroll
        for (int k2 = 0; k2 < 4; ++k2) {
            int i = i0 + k2;
            int wp = w0 + i;
            int jmn = (wp < 16) ? 0 : (wp - 2) / 14; int jmx = wp / 14; if (jmx > 8) jmx = 8;
            float inv = 1.0f / (float)((imax - imin + 1) * (jmx - jmn + 1));
            float val = xf[c * 65 + i] * inv;
            xf[c * 65 + i] = val;
            t4.hh[k2] = f2b(val);
        }
        *(uint2*)(x2w + (size_t)(b * C_ + c) * N_ + nb + i0) = t4.u;
    }
    __syncthreads();
    {
        int i = tid & 63, r = tid >> 6;
        float s = 0.f, ss = 0.f;
        for (int cc = r * 32; cc < r * 32 + 32; ++cc) { float vv = xf[cc * 65 + i]; s += vv; ss += vv * vv; }
        red2[r][i] = s; red2[4 + r][i] = ss;
    }
    __syncthreads();
    if (tid < 64) {
        float s = red2[0][tid] + red2[1][tid] + red2[2][tid] + red2[3][tid];
        float ss = red2[4][tid] + red2[5][tid] + red2[6][tid] + red2[7][tid];
        float mu = s * (1.f / 128.f); float var = ss * (1.f / 128.f) - mu * mu;
        mu_l[tid] = mu; rs_l[tid] = rsqrtf(var + 1e-6f);
    }
    __syncthreads();
    {
        int c = tid & 127;
        float g = lng[c], be = lnb[c];
        for (int e = tid; e < 8192; e += 256) {
            int i = e >> 7;
            float val = (xf[c * 65 + i] - mu_l[i]) * rs_l[i] * g + be;
            *(bf16*)(lds + i * 256 + ((2 * c) ^ ((i & 7) << 4))) = f2b(val);
        }
    }
    __syncthreads();
    bf16x8 afr[4];
    {
        int row = w * 16 + l15;
        #pragma unroll
        for (int cc = 0; cc < 4; ++cc) {
            int cbyt = cc * 64 + lhi * 16;
            afr[cc] = *(const bf16x8*)(lds + row * 256 + (cbyt ^ ((row & 7) << 4)));
        }
    }
    for (int p = 0; p < 2; ++p) {
        __syncthreads();
        for (int e = tid; e < 2048; e += 256) {
            int row = e >> 4, slot = e & 15;
            uint4 val = *(const uint4*)((const char*)wt1 + (size_t)(p * 128 + row) * 256 + slot * 16);
            *(uint4*)(wch + row * 256 + ((slot * 16) ^ ((row & 7) << 4))) = val;
        }
        __syncthreads();
        f32x4 acc[8];
        #pragma unroll
        for (int t = 0; t < 8; ++t) acc[t] = (f32x4){0.f, 0.f, 0.f, 0.f};
        #pragma unroll
        for (int ot = 0; ot < 8; ++ot) {
            int row = ot * 16 + l15;
            #pragma unroll
            for (int cc = 0; cc < 4; ++cc) {
                int cbyt = cc * 64 + lhi * 16;
                bf16x8 bfr = *(const bf16x8*)(wch + row * 256 + (cbyt ^ ((row & 7) << 4)));
                acc[ot] = __builtin_amdgcn_mfma_f32_16x16x32_bf16(afr[cc], bfr, acc[ot], 0, 0, 0);
            }
        }
        int n0 = nb + w * 16 + lhi * 4;
        #pragma unroll
        for (int ot = 0; ot < 8; ++ot) {
            int o = p * 128 + ot * 16 + l15;
            float bi = b1[o];
            union { bf16 h[4]; uint2 u; } t4;
            #pragma unroll
            for (int r = 0; r < 4; ++r) t4.h[r] = f2b(gelu_f(acc[ot][r] + bi));
            *(uint2*)(h1 + (size_t)(b * 256 + o) * N_ + n0) = t4.u;
        }
    }
}

// ---------------- K10: h2 = h1 + dwconv5x5(h1) + dw_b  full-plane LDS (bf16) ----------------
__global__ __launch_bounds__(256) void k_dw5p(const bf16* __restrict__ h1, const float* __restrict__ wdw,
                                              const float* __restrict__ bdw, bf16* __restrict__ h2) {
    __shared__ __align__(16) char tile[38016];     // 132 rows x 288B
    int tid = threadIdx.x;
    int bid = blockIdx.x;                          // 2048 = 8b * 256ch
    int ch = bid & 255, b = bid >> 8;
    const bf16* p = h1 + (size_t)(b * 256 + ch) * N_;
    for (int e = tid; e < 2376; e += 256) *(uint4*)(tile + e * 16) = (uint4){0, 0, 0, 0};
    __syncthreads();
    for (int e = tid; e < 2048; e += 256) {
        int gr = e >> 4, slot = e & 15;
        uint4 val = *(const uint4*)(p + gr * 128 + slot * 8);
        *(uint4*)(tile + (gr + 2) * 288 + 16 + slot * 16) = val;
    }
    float kw[25];
    #pragma unroll
    for (int j = 0; j < 25; ++j) kw[j] = wdw[ch * 25 + j];
    float bi = bdw[ch];
    __syncthreads();
    int hg = tid >> 4, wg = tid & 15;
    int h0 = hg * 8;
    float ring[5][12];
    #pragma unroll
    for (int j = 0; j < 4; ++j) load_row12(tile, h0 + j, wg, ring[j]);
    bf16* op = h2 + (size_t)(b * 256 + ch) * N_;
    #pragma unroll
    for (int rr = 0; rr < 8; ++rr) {
        load_row12(tile, h0 + rr + 4, wg, ring[(rr + 4) % 5]);
        float acc[8];
        #pragma unroll
        for (int ow = 0; ow < 8; ++ow) acc[ow] = bi;
        #pragma unroll
        for (int ky = 0; ky < 5; ++ky) {
            const float* e = ring[(rr + ky) % 5];
            #pragma unroll
            for (int ow = 0; ow < 8; ++ow) {
                #pragma unroll
                for (int kx = 0; kx < 5; ++kx)
                    acc[ow] = fmaf(kw[ky * 5 + kx], e[ow + kx], acc[ow]);
            }
        }
        {
            const float* e = ring[(rr + 2) % 5];
            #pragma unroll
            for (int ow = 0; ow < 8; ++ow) acc[ow] += e[ow + 2];
        }
        union { bf16 h[8]; uint4 u; } outv;
        #pragma unroll
        for (int ow = 0; ow < 8; ++ow) outv.h[ow] = f2b(acc[ow]);
        *(uint4*)(op + (h0 + rr) * 128 + wg * 8) = outv.u;
    }
}

// ---------------- K11: fc2 MFMA GEMM (K=256) + bias + residual -> d_out (fp32) ----------------
__global__ __launch_bounds__(256) void k_fc2_mfma(const bf16* __restrict__ h2, const bf16* __restrict__ wt2,
                                                  const float* __restrict__ b2, const bf16* __restrict__ x2,
                                                  float* __restrict__ out) {
    __shared__ __align__(16) char lds[65536];   // [0,32K): A tile [64][512B]; [32K,64K): W half
    int tid = threadIdx.x;
    int lane = tid & 63, w = tid >> 6;
    int l15 = lane & 15, lhi = lane >> 4;
    int gtok = blockIdx.x * 64; int b = gtok >> 14; int nb = gtok & (N_ - 1);
    char* wch = lds + 32768;
    for (int e = tid; e < 16384; e += 256) {
        int c = e >> 6, i = e & 63;
        bf16 val = h2[(size_t)(b * 256 + c) * N_ + nb + i];
        *(bf16*)(lds + i * 512 + ((2 * c) ^ ((i & 7) << 4))) = val;
    }
    __syncthreads();
    bf16x8 afr[8];
    {
        int row = w * 16 + l15;
        #pragma unroll
        for (int cc = 0; cc < 8; ++cc) {
            int cbyt = cc * 64 + lhi * 16;
            afr[cc] = *(const bf16x8*)(lds + row * 512 + (cbyt ^ ((row & 7) << 4)));
        }
    }
    f32x4 acc[8];
    #pragma unroll
    for (int t = 0; t < 8; ++t) acc[t] = (f32x4){0.f, 0.f, 0.f, 0.f};
    for (int kh = 0; kh < 2; ++kh) {
        __syncthreads();
        for (int e = tid; e < 2048; e += 256) {
            int row = e >> 4, slot = e & 15;
            uint4 val = *(const uint4*)((const char*)wt2 + (size_t)row * 512 + kh * 256 + slot * 16);
            *(uint4*)(wch + row * 256 + ((slot * 16) ^ ((row & 7) << 4))) = val;
        }
        __syncthreads();
        #pragma unroll
        for (int ot = 0; ot < 8; ++ot) {
            int row = ot * 16 + l15;
            #pragma unroll
            for (int cc = 0; cc < 4; ++cc) {
                int cbyt = cc * 64 + lhi * 16;
                bf16x8 bfr = *(const bf16x8*)(wch + row * 256 + (cbyt ^ ((row & 7) << 4)));
                acc[ot] = __builtin_amdgcn_mfma_f32_16x16x32_bf16(afr[kh * 4 + cc], bfr, acc[ot], 0, 0, 0);
            }
        }
    }
    int n0 = nb + w * 16 + lhi * 4;
    #pragma unroll
    for (int ot = 0; ot < 8; ++ot) {
        int o = ot * 16 + l15;
        size_t obase = (size_t)(b * C_ + o) * N_ + n0;
        float bi = b2[o];
        union { uint2 u; bf16 h[4]; } xr;
        xr.u = *(const uint2*)(x2 + obase);
        float4 r4;
        r4.x = acc[ot][0] + bi + b2f(xr.h[0]);
        r4.y = acc[ot][1] + bi + b2f(xr.h[1]);
        r4.z = acc[ot][2] + bi + b2f(xr.h[2]);
        r4.w = acc[ot][3] + bi + b2f(xr.h[3]);
        *(float4*)(out + obase) = r4;
    }
}

extern "C" void kernel_launch(void* const* d_in, const int* in_sizes, int n_in,
                              void* d_out, int out_size, void* d_ws, size_t ws_size,
                              hipStream_t stream) {
    const float* x         = (const float*)d_in[0];
    const float* lth_dw_w  = (const float*)d_in[2];
    const float* lth_pw_w  = (const float*)d_in[3];
    const float* lth_pw_b  = (const float*)d_in[4];
    const float* lth_gate_w= (const float*)d_in[5];
    const float* lth_gate_b= (const float*)d_in[6];
    const float* lth_scale = (const float*)d_in[7];
    const float* ln1_g     = (const float*)d_in[8];
    const float* ln1_b     = (const float*)d_in[9];
    const float* ln2_g     = (const float*)d_in[10];
    const float* ln2_b     = (const float*)d_in[11];
    const float* qkv_w     = (const float*)d_in[12];
    const float* gate_w    = (const float*)d_in[13];
    const float* gate_b    = (const float*)d_in[14];
    const float* proj_w    = (const float*)d_in[15];
    const float* pe_w      = (const float*)d_in[16];
    const float* pe_b      = (const float*)d_in[17];
    const float* fc1_w     = (const float*)d_in[18];
    const float* fc1_b     = (const float*)d_in[19];
    const float* dw_w      = (const float*)d_in[20];
    const float* dw_b      = (const float*)d_in[21];
    const float* fc2_w     = (const float*)d_in[22];
    const float* fc2_b     = (const float*)d_in[23];

    // Slab plan (bytes), peak ~234.5 MiB (proven R13):
    //  A: x1 ; h2 spans A+B (x1/o dead by dw5p)
    //  B: sg -> o -> u (k_peg in-place)
    //  C: q -> x2 (q dead after peg; x2 written by fc1ln)
    //  D: hf -> k -> t2 (t2 live through fc1ln)
    //  E: g -> v ; h1 spans E+F
    //  F: z
    //  G: wt(32K) H: wqkv(128K) I: wt1(64K) wt2(64K) wpw(32K)
    char* ws = (char*)d_ws;
    constexpr size_t SZ_X = 33554432;    // bf16, 16,777,216 elems
    constexpr size_t SZ_W = 42467328;    // bf16, 21,233,664 elems
    constexpr size_t OFF_A = 0;
    constexpr size_t OFF_B = OFF_A + SZ_X;
    constexpr size_t OFF_C = OFF_B + SZ_W;
    constexpr size_t OFF_D = OFF_C + SZ_W;
    constexpr size_t OFF_E = OFF_D + SZ_W;
    constexpr size_t OFF_F = OFF_E + SZ_W;
    constexpr size_t OFF_G = OFF_F + SZ_W;
    constexpr size_t OFF_H = OFF_G + 32768;
    constexpr size_t OFF_I = OFF_H + 131072;

    bf16*  x1  = (bf16*)(ws + OFF_A);
    bf16*  h2  = (bf16*)(ws + OFF_A);   // spans A+B
    float* sg  = (float*)(ws + OFF_B + 16777216);
    bf16*  o   = (bf16*)(ws + OFF_B);
    bf16*  q   = (bf16*)(ws + OFF_C);
    bf16*  x2  = (bf16*)(ws + OFF_C);
    bf16*  hf  = (bf16*)(ws + OFF_D);
    bf16*  k   = (bf16*)(ws + OFF_D);
    bf16*  t2  = (bf16*)(ws + OFF_D);
    bf16*  g   = (bf16*)(ws + OFF_E);
    bf16*  v   = (bf16*)(ws + OFF_E);
    bf16*  h1  = (bf16*)(ws + OFF_E);   // spans E+F
    bf16*  z   = (bf16*)(ws + OFF_F);
    bf16*  wt  = (bf16*)(ws + OFF_G);
    bf16*  wqkv= (bf16*)(ws + OFF_H);
    bf16*  wt1 = (bf16*)(ws + OFF_I);
    bf16*  wt2 = (bf16*)(ws + OFF_I + 65536);
    bf16*  wpw = (bf16*)(ws + OFF_I + 131072);

    k_wprep   <<<640,   256, 0, stream>>>(proj_w, qkv_w, gate_w, fc1_w, fc2_w, lth_pw_w,
                                          wt, wqkv, wt1, wt2, wpw);
    k_hf2     <<<8192,  256, 0, stream>>>(x, hf);
    k_sgate   <<<512,   256, 0, stream>>>(hf, lth_gate_w, lth_gate_b, sg);
    k_dw3p    <<<1024,  256, 0, stream>>>(hf, lth_dw_w, g);
    k_pw_mfma <<<2048,  256, 0, stream>>>(g, wpw, lth_pw_b, x, lth_scale, sg, x1);
    k_qkv_mfma<<<2592,  256, 0, stream>>>(x1, ln1_g, ln1_b, wqkv, gate_b, q, k, v, z);
    k_attn_mfma<<<2592, 256, 0, stream>>>(q, k, v, o);
    k_peg     <<<10368, 256, 0, stream>>>(o, q, z, pe_w, pe_b);
    k_proj    <<<2592,  256, 0, stream>>>(o, wt, x1, t2);
    k_fc1ln   <<<2048,  256, 0, stream>>>(t2, ln2_g, ln2_b, wt1, fc1_b, h1, x2);
    k_dw5p    <<<2048,  256, 0, stream>>>(h1, dw_w, dw_b, h2);
    k_fc2_mfma<<<2048,  256, 0, stream>>>(h2, wt2, fc2_b, x2, (float*)d_out);
}

// Round 19
// 520.222 us; speedup vs baseline: 1.0183x; 1.0183x over previous
//
#include <hip/hip_runtime.h>
#include <hip/hip_bf16.h>
#include <math.h>

typedef __hip_bfloat16 bf16;
typedef __attribute__((ext_vector_type(8))) short bf16x8;
typedef __attribute__((ext_vector_type(4))) float f32x4;

static constexpr int B_ = 8, C_ = 128, H_ = 128, W_ = 128;
static constexpr int N_ = H_ * W_;          // 16384
static constexpr int NWIN = 648;            // B * 9 * 9

__device__ __forceinline__ float b2f(bf16 v) { return __bfloat162float(v); }
__device__ __forceinline__ bf16 f2b(float v) { return __float2bfloat16(v); }

// erf-free exact-GELU: A&S 7.1.26 rational erf approx (|err|<=1.5e-7), pure FMA + v_exp.
__device__ __forceinline__ float gelu_f(float x) {
    float xs = x * 0.70710678118654752f;
    float ax = fabsf(xs);
    float t = 1.0f / fmaf(0.3275911f, ax, 1.0f);
    float poly = t * fmaf(t, fmaf(t, fmaf(t, fmaf(t, 1.061405429f, -1.453152027f), 1.421413741f), -0.284496736f), 0.254829592f);
    float erf_ax = fmaf(-poly, __expf(-ax * ax), 1.0f);
    float erfv = copysignf(erf_ax, xs);
    return 0.5f * x * (1.0f + erfv);
}

// 12-wide row extraction from padded plane tile (row bytes: [0,16) left pad, [16,272) cols, [272,288) right pad)
__device__ __forceinline__ void load_row12(const char* tile, int a, int wg, float* dst) {
    int base = a * 288 + wg * 16;
    union { uint4 u; bf16 hh[8]; } c0, c1, c2;
    c0.u = *(const uint4*)(tile + base);
    c1.u = *(const uint4*)(tile + base + 16);
    c2.u = *(const uint4*)(tile + base + 32);
    dst[0] = b2f(c0.hh[6]); dst[1] = b2f(c0.hh[7]);
    #pragma unroll
    for (int j = 0; j < 8; ++j) dst[2 + j] = b2f(c1.hh[j]);
    dst[10] = b2f(c2.hh[0]); dst[11] = b2f(c2.hh[1]);
}

// ---------------- K0: all weight preps merged (one-off) ----------------
__global__ __launch_bounds__(256) void k_wprep(const float* __restrict__ projw, const float* __restrict__ qkvw,
                                               const float* __restrict__ gatew, const float* __restrict__ w1,
                                               const float* __restrict__ w2, const float* __restrict__ pww,
                                               bf16* __restrict__ wt, bf16* __restrict__ wqkv,
                                               bf16* __restrict__ wt1, bf16* __restrict__ wt2,
                                               bf16* __restrict__ wpw) {
    int idx = blockIdx.x * 256 + threadIdx.x;    // 163840
    if (idx < 16384) {
        int o = idx >> 7, c = idx & 127;
        wt[idx] = f2b(projw[c * 128 + o]);
    } else if (idx < 81920) {
        int i = idx - 16384; int o = i >> 7, c = i & 127;
        wqkv[i] = f2b((o < 384) ? qkvw[c * 384 + o] : gatew[c * 128 + (o - 384)]);
    } else if (idx < 114688) {
        int i = idx - 81920; int o = i >> 7, c = i & 127;
        wt1[i] = f2b(w1[c * 256 + o]);
    } else if (idx < 147456) {
        int i = idx - 114688; int o = i >> 8, c = i & 255;
        wt2[i] = f2b(w2[c * 128 + o]);
    } else {
        int i = idx - 147456;
        wpw[i] = f2b(pww[i]);
    }
}

// ---------------- K1: fused 2x2-pool + bilinear-up + hf = x - up (bf16 out) ----------------
__global__ __launch_bounds__(256) void k_hf2(const float* __restrict__ x, bf16* __restrict__ hf) {
    __shared__ float lowt[10][64];
    int tid = threadIdx.x;
    int bid = blockIdx.x;                       // 8192 = 8b * 128c * 8ht
    int ht = bid & 7, c = (bid >> 3) & 127, b = bid >> 10;
    const float* xp = x + (size_t)(b * C_ + c) * N_;
    int h0 = ht * 16;
    int lo0 = (h0 >> 1) - 1;
    for (int e = tid; e < 640; e += 256) {
        int lr = e >> 6, jc = e & 63;
        int j = lo0 + lr; j = j < 0 ? 0 : (j > 63 ? 63 : j);
        const float* pr = xp + (2 * j) * W_ + 2 * jc;
        lowt[lr][jc] = (pr[0] + pr[1] + pr[W_] + pr[W_ + 1]) * 0.25f;
    }
    __syncthreads();
    int hl = tid >> 4, wg = tid & 15;
    int h = h0 + hl;
    int jh = h >> 1;
    int j0, j1; float wh0, wh1;
    if (h & 1) { j0 = jh; j1 = jh + 1 > 63 ? 63 : jh + 1; wh0 = 0.75f; wh1 = 0.25f; }
    else       { j0 = jh - 1 < 0 ? 0 : jh - 1; j1 = jh;   wh0 = 0.25f; wh1 = 0.75f; }
    int l0 = j0 - lo0, l1 = j1 - lo0;
    float4 xa = *(const float4*)(xp + h * W_ + wg * 8);
    float4 xb = *(const float4*)(xp + h * W_ + wg * 8 + 4);
    float xv[8] = {xa.x, xa.y, xa.z, xa.w, xb.x, xb.y, xb.z, xb.w};
    union { bf16 hh[8]; uint4 u; } outv;
    #pragma unroll
    for (int k2 = 0; k2 < 8; ++k2) {
        int w = wg * 8 + k2;
        int jw = w >> 1;
        int w0, w1; float ww0, ww1;
        if (w & 1) { w0 = jw; w1 = jw + 1 > 63 ? 63 : jw + 1; ww0 = 0.75f; ww1 = 0.25f; }
        else       { w0 = jw - 1 < 0 ? 0 : jw - 1; w1 = jw;   ww0 = 0.25f; ww1 = 0.75f; }
        float up = wh0 * (ww0 * lowt[l0][w0] + ww1 * lowt[l0][w1])
                 + wh1 * (ww0 * lowt[l1][w0] + ww1 * lowt[l1][w1]);
        outv.hh[k2] = f2b(xv[k2] - up);
    }
    *(uint4*)(hf + (size_t)(b * C_ + c) * N_ + h * W_ + wg * 8) = outv.u;
}

// ---------------- K2: sgate (fp32 out) ----------------
__global__ __launch_bounds__(256) void k_sgate(const bf16* __restrict__ hf, const float* __restrict__ gw,
                                               const float* __restrict__ gb, float* __restrict__ sg) {
    int idx = blockIdx.x * 256 + threadIdx.x;       // 131072
    int n = idx & (N_ - 1); int b = idx >> 14;
    const bf16* p = hf + (size_t)b * C_ * N_ + n;
    float s = 0.f;
    for (int c = 0; c < C_; ++c) s += gw[c] * fabsf(b2f(p[(size_t)c * N_]));
    s += gb[0];
    sg[idx] = 1.0f / (1.0f + __expf(-s));
}

// ---------------- K3: g = gelu(dwconv3x3 dil2) full-plane LDS (bf16) ----------------
__global__ __launch_bounds__(256) void k_dw3p(const bf16* __restrict__ hf, const float* __restrict__ wdw,
                                              bf16* __restrict__ g) {
    __shared__ __align__(16) char tile[38016];     // 132 rows x 288B (8-col zero pads each side)
    int tid = threadIdx.x;
    int bid = blockIdx.x;                          // 1024 = 8b * 128c
    int ch = bid & 127, b = bid >> 7;
    const bf16* p = hf + (size_t)(b * C_ + ch) * N_;
    for (int e = tid; e < 2376; e += 256) *(uint4*)(tile + e * 16) = (uint4){0, 0, 0, 0};
    __syncthreads();
    for (int e = tid; e < 2048; e += 256) {
        int gr = e >> 4, slot = e & 15;
        uint4 val = *(const uint4*)(p + gr * 128 + slot * 8);
        *(uint4*)(tile + (gr + 2) * 288 + 16 + slot * 16) = val;
    }
    float kw[9];
    #pragma unroll
    for (int j = 0; j < 9; ++j) kw[j] = wdw[ch * 9 + j];
    __syncthreads();
    int hg = tid >> 4, wg = tid & 15;
    int h0 = hg * 8;
    float ring[5][12];
    #pragma unroll
    for (int j = 0; j < 4; ++j) load_row12(tile, h0 + j, wg, ring[j]);
    bf16* op = g + (size_t)(b * C_ + ch) * N_;
    #pragma unroll
    for (int rr = 0; rr < 8; ++rr) {
        load_row12(tile, h0 + rr + 4, wg, ring[(rr + 4) % 5]);
        float acc[8] = {};
        #pragma unroll
        for (int ky = 0; ky < 3; ++ky) {
            const float* e = ring[(rr + 2 * ky) % 5];
            #pragma unroll
            for (int ow = 0; ow < 8; ++ow) {
                acc[ow] = fmaf(kw[ky * 3 + 0], e[ow], acc[ow]);
                acc[ow] = fmaf(kw[ky * 3 + 1], e[ow + 2], acc[ow]);
                acc[ow] = fmaf(kw[ky * 3 + 2], e[ow + 4], acc[ow]);
            }
        }
        union { bf16 h[8]; uint4 u; } outv;
        #pragma unroll
        for (int ow = 0; ow < 8; ++ow) outv.h[ow] = f2b(gelu_f(acc[ow]));
        *(uint4*)(op + (h0 + rr) * 128 + wg * 8) = outv.u;
    }
}

// ---------------- K4: pw MFMA GEMM + LTH epilogue -> x1 (bf16) ----------------
__global__ __launch_bounds__(256) void k_pw_mfma(const bf16* __restrict__ g, const bf16* __restrict__ wpw,
                                                 const float* __restrict__ pwb, const float* __restrict__ x,
                                                 const float* __restrict__ scale, const float* __restrict__ sg,
                                                 bf16* __restrict__ x1) {
    __shared__ __align__(16) char lds[49152];   // [0,16K): A tile; [16K,48K): W
    int tid = threadIdx.x;
    int lane = tid & 63, w = tid >> 6;
    int l15 = lane & 15, lhi = lane >> 4;
    int gtok = blockIdx.x * 64; int b = gtok >> 14; int nb = gtok & (N_ - 1);
    char* wch = lds + 16384;
    for (int e = tid; e < 8192; e += 256) {
        int c = e >> 6, i = e & 63;
        bf16 val = g[(size_t)(b * C_ + c) * N_ + nb + i];
        *(bf16*)(lds + i * 256 + ((2 * c) ^ ((i & 7) << 4))) = val;
    }
    for (int e = tid; e < 2048; e += 256) {
        int row = e >> 4, slot = e & 15;
        uint4 val = *(const uint4*)((const char*)wpw + row * 256 + slot * 16);
        *(uint4*)(wch + row * 256 + ((slot * 16) ^ ((row & 7) << 4))) = val;
    }
    __syncthreads();
    bf16x8 afr[4];
    {
        int row = w * 16 + l15;
        #pragma unroll
        for (int cc = 0; cc < 4; ++cc) {
            int cbyt = cc * 64 + lhi * 16;
            afr[cc] = *(const bf16x8*)(lds + row * 256 + (cbyt ^ ((row & 7) << 4)));
        }
    }
    f32x4 acc[8];
    #pragma unroll
    for (int t = 0; t < 8; ++t) acc[t] = (f32x4){0.f, 0.f, 0.f, 0.f};
    #pragma unroll
    for (int ot = 0; ot < 8; ++ot) {
        int row = ot * 16 + l15;
        #pragma unroll
        for (int cc = 0; cc < 4; ++cc) {
            int cbyt = cc * 64 + lhi * 16;
            bf16x8 bfr = *(const bf16x8*)(wch + row * 256 + (cbyt ^ ((row & 7) << 4)));
            acc[ot] = __builtin_amdgcn_mfma_f32_16x16x32_bf16(afr[cc], bfr, acc[ot], 0, 0, 0);
        }
    }
    int n0 = nb + w * 16 + lhi * 4;
    float4 sg4 = *(const float4*)&sg[b * N_ + n0];
    #pragma unroll
    for (int ot = 0; ot < 8; ++ot) {
        int o = ot * 16 + l15;
        size_t obase = (size_t)(b * C_ + o) * N_ + n0;
        float4 x4 = *(const float4*)&x[obase];
        float sc = scale[o], bi = pwb[o];
        union { bf16 h[4]; uint2 u; } t4;
        t4.h[0] = f2b(x4.x + sc * (acc[ot][0] + bi) * sg4.x);
        t4.h[1] = f2b(x4.y + sc * (acc[ot][1] + bi) * sg4.y);
        t4.h[2] = f2b(x4.z + sc * (acc[ot][2] + bi) * sg4.z);
        t4.h[3] = f2b(x4.w + sc * (acc[ot][3] + bi) * sg4.w);
        *(uint2*)(x1 + obase) = t4.u;
    }
}

// ---------------- K5: LN1 + qkv/gate MFMA GEMM -> q,k,z [tok][c]; v [c][tok] ----------------
// R19: reverted to the R14/R17 form (proven deterministic, 93us). R18's LDS repack was a
// misdiagnosis: WRITE_SIZE 166MB is the intrinsic write volume (q+k+v+z = 170MB), not
// amplification; the repack added bank-conflicted ds_writes + barriers for nothing.
__global__ __launch_bounds__(256) void k_qkv_mfma(const bf16* __restrict__ x1, const float* __restrict__ lng,
                                                  const float* __restrict__ lnb, const bf16* __restrict__ wall,
                                                  const float* __restrict__ gateb,
                                                  bf16* __restrict__ q, bf16* __restrict__ k,
                                                  bf16* __restrict__ v, bf16* __restrict__ z) {
    __shared__ __align__(16) char lds[49664];   // [0,16K): y bf16 swizzled; [16K,...): xf fp32 [128][65] -> w chunk
    __shared__ float red2[8][64];
    __shared__ float mu_l[64], rs_l[64];
    int tid = threadIdx.x;
    int lane = tid & 63, w = tid >> 6;
    int l15 = lane & 15, lhi = lane >> 4;
    int win = blockIdx.x >> 2; int qbase = (blockIdx.x & 3) * 64;
    int b = win / 81; int r0 = win % 81; int top = (r0 / 9) * 14, left = (r0 % 9) * 14;
    float* xf = (float*)(lds + 16384);           // [128][65] fp32
    char* wchunk = lds + 16384;                  // same region, after xf dies
    for (int e = tid; e < 8192; e += 256) {
        int c = e >> 6, i = e & 63; int tok = qbase + i; int p = tok >> 4, qq = tok & 15;
        xf[c * 65 + i] = b2f(x1[(size_t)(b * C_ + c) * N_ + (top + p) * W_ + (left + qq)]);
    }
    __syncthreads();
    {
        int i = tid & 63, r = tid >> 6;
        float s = 0.f, ss = 0.f;
        for (int cc = r * 32; cc < r * 32 + 32; ++cc) { float vv = xf[cc * 65 + i]; s += vv; ss += vv * vv; }
        red2[r][i] = s; red2[4 + r][i] = ss;
    }
    __syncthreads();
    if (tid < 64) {
        float s = red2[0][tid] + red2[1][tid] + red2[2][tid] + red2[3][tid];
        float ss = red2[4][tid] + red2[5][tid] + red2[6][tid] + red2[7][tid];
        float mu = s * (1.f / 128.f); float var = ss * (1.f / 128.f) - mu * mu;
        mu_l[tid] = mu; rs_l[tid] = rsqrtf(var + 1e-6f);
    }
    __syncthreads();
    {
        int c = tid & 127;
        float g = lng[c], be = lnb[c];
        for (int e = tid; e < 8192; e += 256) {
            int i = e >> 7;
            float val = (xf[c * 65 + i] - mu_l[i]) * rs_l[i] * g + be;
            *(bf16*)(lds + i * 256 + ((2 * c) ^ ((i & 7) << 4))) = f2b(val);
        }
    }
    __syncthreads();
    bf16x8 afr[4];
    {
        int row = w * 16 + l15;
        #pragma unroll
        for (int cc = 0; cc < 4; ++cc) {
            int cbyt = cc * 64 + lhi * 16;
            afr[cc] = *(const bf16x8*)(lds + row * 256 + (cbyt ^ ((row & 7) << 4)));
        }
    }
    for (int pass = 0; pass < 4; ++pass) {
        __syncthreads();
        for (int e = tid; e < 2048; e += 256) {
            int row = e >> 4, slot = e & 15;
            uint4 val = *(const uint4*)((const char*)wall + (size_t)(pass * 128 + row) * 256 + slot * 16);
            *(uint4*)(wchunk + row * 256 + ((slot * 16) ^ ((row & 7) << 4))) = val;
        }
        __syncthreads();
        f32x4 acc[8];
        #pragma unroll
        for (int t = 0; t < 8; ++t) acc[t] = (f32x4){0.f, 0.f, 0.f, 0.f};
        #pragma unroll
        for (int ot = 0; ot < 8; ++ot) {
            int row = ot * 16 + l15;
            #pragma unroll
            for (int cc = 0; cc < 4; ++cc) {
                int cbyt = cc * 64 + lhi * 16;
                bf16x8 bfr = *(const bf16x8*)(wchunk + row * 256 + (cbyt ^ ((row & 7) << 4)));
                acc[ot] = __builtin_amdgcn_mfma_f32_16x16x32_bf16(afr[cc], bfr, acc[ot], 0, 0, 0);
            }
        }
        if (pass != 2) {
            bf16* outp = (pass == 0) ? q : (pass == 1) ? k : z;   // [win][tok][c]
            bool gel = (pass == 3);
            #pragma unroll
            for (int ot = 0; ot < 8; ++ot) {
                int o = ot * 16 + l15;
                float gb = gel ? gateb[o] : 0.f;
                #pragma unroll
                for (int r = 0; r < 4; ++r) {
                    int gtok = qbase + w * 16 + lhi * 4 + r;
                    float vv = acc[ot][r];
                    outp[((size_t)win * 256 + gtok) * 128 + o] = gel ? f2b(gelu_f(vv + gb)) : f2b(vv);
                }
            }
        } else {                                  // v: [win][c][tok]
            #pragma unroll
            for (int ot = 0; ot < 8; ++ot) {
                int o = ot * 16 + l15;
                union { bf16 h[4]; uint2 u; } t4;
                #pragma unroll
                for (int r = 0; r < 4; ++r) t4.h[r] = f2b(acc[ot][r]);
                *(uint2*)(v + (size_t)win * 32768 + (size_t)o * 256 + qbase + w * 16 + lhi * 4) = t4.u;
            }
        }
    }
}

// ---------------- K6: MFMA attention core: softmax(QK^T*scale)V -> o [win][tok][c] ----------------
// R15 (validated): XCD-aware block map (4 quarters of a window share an XCD -> k/v L2 reuse);
// PV operand swap -> packed uint2 o-stores.
__global__ __launch_bounds__(256) void k_attn_mfma(const bf16* __restrict__ qb, const bf16* __restrict__ kb,
                                                   const bf16* __restrict__ vb, bf16* __restrict__ ob) {
    __shared__ __align__(16) char lds[49152];   // [0,32K): q (16K) then P (32K); [32K,48K): K/V chunk
    int tid = threadIdx.x;
    int lane = tid & 63, w = tid >> 6;
    int l15 = lane & 15, lhi = lane >> 4;
    int xcd = blockIdx.x & 7, ixd = blockIdx.x >> 3;   // 648 windows = 8 XCDs x 81
    int win = xcd * 81 + (ixd >> 2);
    int qbase = (ixd & 3) * 64;
    const bf16* qg = qb + ((size_t)win * 256 + qbase) * 128;   // [64][128]
    const bf16* kg = kb + (size_t)win * 256 * 128;             // [256][128]
    const bf16* vg = vb + (size_t)win * 128 * 256;             // [128][256]
    char* chunk = lds + 32768;
    for (int e = tid; e < 1024; e += 256) {
        int row = e >> 4, slot = e & 15;
        uint4 val = *(const uint4*)((const char*)qg + row * 256 + slot * 16);
        *(uint4*)(lds + row * 256 + ((slot * 16) ^ ((row & 7) << 4))) = val;
    }
    __syncthreads();
    bf16x8 afr[4];
    {
        int row = w * 16 + l15;
        #pragma unroll
        for (int cc = 0; cc < 4; ++cc) {
            int cb = cc * 64 + lhi * 16;
            afr[cc] = *(const bf16x8*)(lds + row * 256 + (cb ^ ((row & 7) << 4)));
        }
    }
    f32x4 acc[16];
    #pragma unroll
    for (int t = 0; t < 16; ++t) acc[t] = (f32x4){0.f, 0.f, 0.f, 0.f};
    for (int kc = 0; kc < 4; ++kc) {
        __syncthreads();
        for (int e = tid; e < 1024; e += 256) {
            int row = e >> 4, slot = e & 15;
            uint4 val = *(const uint4*)((const char*)kg + (size_t)(kc * 64 + row) * 256 + slot * 16);
            *(uint4*)(chunk + row * 256 + ((slot * 16) ^ ((row & 7) << 4))) = val;
        }
        __syncthreads();
        #pragma unroll
        for (int t = 0; t < 4; ++t) {
            int row = t * 16 + l15;
            #pragma unroll
            for (int cc = 0; cc < 4; ++cc) {
                int cb = cc * 64 + lhi * 16;
                bf16x8 bfr = *(const bf16x8*)(chunk + row * 256 + (cb ^ ((row & 7) << 4)));
                acc[kc * 4 + t] = __builtin_amdgcn_mfma_f32_16x16x32_bf16(afr[cc], bfr, acc[kc * 4 + t], 0, 0, 0);
            }
        }
    }
    const float sm_scale = 0.08838834764831845f;   // 128^-0.5
    #pragma unroll
    for (int r = 0; r < 4; ++r) {
        float m = -1e30f;
        #pragma unroll
        for (int t = 0; t < 16; ++t) m = fmaxf(m, acc[t][r]);
        #pragma unroll
        for (int d2 = 1; d2 < 16; d2 <<= 1) m = fmaxf(m, __shfl_xor(m, d2, 64));
        float ssum = 0.f;
        #pragma unroll
        for (int t = 0; t < 16; ++t) { float p = __expf((acc[t][r] - m) * sm_scale); acc[t][r] = p; ssum += p; }
        #pragma unroll
        for (int d2 = 1; d2 < 16; d2 <<= 1) ssum += __shfl_xor(ssum, d2, 64);
        float inv = 1.f / ssum;
        #pragma unroll
        for (int t = 0; t < 16; ++t) acc[t][r] *= inv;
    }
    #pragma unroll
    for (int t = 0; t < 16; ++t) {
        #pragma unroll
        for (int r = 0; r < 4; ++r) {
            int row = w * 16 + lhi * 4 + r;
            int cb = (t * 16 + l15) * 2;
            *(bf16*)(lds + row * 512 + (cb ^ ((row & 7) << 4))) = f2b(acc[t][r]);
        }
    }
    f32x4 oacc[8];
    #pragma unroll
    for (int t = 0; t < 8; ++t) oacc[t] = (f32x4){0.f, 0.f, 0.f, 0.f};
    for (int vc = 0; vc < 4; ++vc) {
        __syncthreads();
        for (int e = tid; e < 1024; e += 256) {
            int row = e >> 3, slot = e & 7;
            uint4 val = *(const uint4*)((const char*)vg + (size_t)row * 512 + vc * 128 + slot * 16);
            *(uint4*)(chunk + row * 128 + ((slot * 16) ^ ((row & 7) << 4))) = val;
        }
        __syncthreads();
        #pragma unroll
        for (int jc = 0; jc < 2; ++jc) {
            int prow = w * 16 + l15;
            int pcb = vc * 128 + jc * 64 + lhi * 16;
            bf16x8 ap = *(const bf16x8*)(lds + prow * 512 + (pcb ^ ((prow & 7) << 4)));
            #pragma unroll
            for (int ct = 0; ct < 8; ++ct) {
                int vrow = ct * 16 + l15;
                int vcb = jc * 64 + lhi * 16;
                bf16x8 bv = *(const bf16x8*)(chunk + vrow * 128 + (vcb ^ ((vrow & 7) << 4)));
                // swapped: D[c][tok] -> c contiguous per thread
                oacc[ct] = __builtin_amdgcn_mfma_f32_16x16x32_bf16(bv, ap, oacc[ct], 0, 0, 0);
            }
        }
    }
    bf16* og = ob + ((size_t)win * 256 + qbase) * 128;
    {
        int tok = w * 16 + l15;
        #pragma unroll
        for (int ct = 0; ct < 8; ++ct) {
            int c4 = ct * 16 + lhi * 4;
            union { bf16 h[4]; uint2 u; } t4;
            #pragma unroll
            for (int r = 0; r < 4; ++r) t4.h[r] = f2b(oacc[ct][r]);
            *(uint2*)(og + tok * 128 + c4) = t4.u;
        }
    }
}

// ---------------- K7: fused PE+gate + proj MFMA GEMM + crop residual -> t2 [win][c][tok] ----------------
// R19: k_peg merged into staging — u = (o + PE(q))*z computed while building the A tile.
// Saves the o in-place rewrite (42MB W) + re-read (42MB R) + a 10368-block launch.
__global__ __launch_bounds__(256) void k_proj(const bf16* __restrict__ ob, const bf16* __restrict__ qb,
                                              const bf16* __restrict__ zb, const bf16* __restrict__ wt,
                                              const bf16* __restrict__ x1,
                                              const float* __restrict__ pew, const float* __restrict__ peb,
                                              bf16* __restrict__ t2) {
    __shared__ __align__(16) char lds[49152];   // [0,16K): u tile; [16K,48K): wt tile
    __shared__ float pw_lds[1152];
    __shared__ float pb_lds[128];
    int tid = threadIdx.x;
    int lane = tid & 63, w = tid >> 6;
    int l15 = lane & 15, lhi = lane >> 4;
    int win = blockIdx.x >> 2, qbase = (blockIdx.x & 3) * 64;
    int b = win / 81; int r0 = win % 81; int top = (r0 / 9) * 14, left = (r0 % 9) * 14;
    char* wchunk = lds + 16384;
    // stage PE weights
    for (int e = tid; e < 1152; e += 256) pw_lds[e] = pew[e];
    if (tid < 128) pb_lds[tid] = peb[tid];
    // stage W tile (independent of pe weights)
    for (int e = tid; e < 2048; e += 256) {
        int row = e >> 4, slot = e & 15;
        uint4 val = *(const uint4*)((const char*)wt + row * 256 + slot * 16);
        *(uint4*)(wchunk + row * 256 + ((slot * 16) ^ ((row & 7) << 4))) = val;
    }
    __syncthreads();   // pe weights visible
    // stage u tile: u = (o + PE(q)) * z, computed per 16B slot
    for (int e = tid; e < 1024; e += 256) {
        int row = e >> 4, slot = e & 15;       // row = local tok, slot = 8-channel group
        int gtok = qbase + row;
        int pp = gtok >> 4, qq = gtok & 15;
        int cb = slot * 8;
        float pv[8];
        #pragma unroll
        for (int cc = 0; cc < 8; ++cc) pv[cc] = pb_lds[cb + cc];
        #pragma unroll
        for (int ky = 0; ky < 3; ++ky) {
            int py = pp + ky - 1; if ((unsigned)py >= 16u) continue;
            #pragma unroll
            for (int kx = 0; kx < 3; ++kx) {
                int qx = qq + kx - 1; if ((unsigned)qx >= 16u) continue;
                union { uint4 u; bf16 h[8]; } qu;
                qu.u = *(const uint4*)(qb + ((size_t)win * 256 + py * 16 + qx) * 128 + cb);
                #pragma unroll
                for (int cc = 0; cc < 8; ++cc)
                    pv[cc] += pw_lds[(cb + cc) * 9 + ky * 3 + kx] * b2f(qu.h[cc]);
            }
        }
        union { uint4 u; bf16 h[8]; } ou, zu, uu;
        ou.u = *(const uint4*)(ob + ((size_t)win * 256 + gtok) * 128 + cb);
        zu.u = *(const uint4*)(zb + ((size_t)win * 256 + gtok) * 128 + cb);
        #pragma unroll
        for (int cc = 0; cc < 8; ++cc)
            uu.h[cc] = f2b((b2f(ou.h[cc]) + pv[cc]) * b2f(zu.h[cc]));
        *(uint4*)(lds + row * 256 + ((slot * 16) ^ ((row & 7) << 4))) = uu.u;
    }
    __syncthreads();
    bf16x8 afr[4];
    {
        int row = w * 16 + l15;
        #pragma unroll
        for (int cc = 0; cc < 4; ++cc) {
            int cbyt = cc * 64 + lhi * 16;
            afr[cc] = *(const bf16x8*)(lds + row * 256 + (cbyt ^ ((row & 7) << 4)));
        }
    }
    f32x4 acc[8];
    #pragma unroll
    for (int t = 0; t < 8; ++t) acc[t] = (f32x4){0.f, 0.f, 0.f, 0.f};
    #pragma unroll
    for (int ot = 0; ot < 8; ++ot) {
        int row = ot * 16 + l15;
        #pragma unroll
        for (int cc = 0; cc < 4; ++cc) {
            int cbyt = cc * 64 + lhi * 16;
            bf16x8 bfr = *(const bf16x8*)(wchunk + row * 256 + (cbyt ^ ((row & 7) << 4)));
            acc[ot] = __builtin_amdgcn_mfma_f32_16x16x32_bf16(afr[cc], bfr, acc[ot], 0, 0, 0);
        }
    }
    int gtok0 = qbase + w * 16 + lhi * 4;
    int p = gtok0 >> 4, qq = gtok0 & 15;       // qq = lhi*4; qq+3 <= 15, row not crossed
    #pragma unroll
    for (int ot = 0; ot < 8; ++ot) {
        int o = ot * 16 + l15;
        const uint* xr32 = (const uint*)(x1 + (size_t)(b * C_ + o) * N_ + (top + p) * W_ + left + qq);
        union { uint u2[2]; bf16 h[4]; } xv;
        xv.u2[0] = xr32[0]; xv.u2[1] = xr32[1];
        union { bf16 h[4]; uint2 u; } t4;
        #pragma unroll
        for (int r = 0; r < 4; ++r) t4.h[r] = f2b(acc[ot][r] + b2f(xv.h[r]));
        *(uint2*)(t2 + (size_t)win * 32768 + (size_t)o * 256 + gtok0) = t4.u;
    }
}

// ---------------- K8: fused fold + LN2 + fc1 MFMA GEMM + gelu -> h1 (bf16), x2 (bf16) ----------------
__global__ __launch_bounds__(256) void k_fc1ln(const bf16* __restrict__ t2, const float* __restrict__ lng,
                                               const float* __restrict__ lnb, const bf16* __restrict__ wt1,
                                               const float* __restrict__ b1, bf16* __restrict__ h1,
                                               bf16* __restrict__ x2w) {
    __shared__ __align__(16) char lds[49664];   // [0,16K): A bf16 swizzled; [16K,...): xf fp32 [128][65] -> w chunk
    __shared__ float red2[8][64];
    __shared__ float mu_l[64], rs_l[64];
    int tid = threadIdx.x;
    int lane = tid & 63, w = tid >> 6;
    int l15 = lane & 15, lhi = lane >> 4;
    int gtok = blockIdx.x * 64; int b = gtok >> 14; int nb = gtok & (N_ - 1);
    int h = nb >> 7, w0 = nb & 127;
    int imin = (h < 16) ? 0 : (h - 2) / 14; int imax = h / 14; if (imax > 8) imax = 8;
    int jmin0 = (w0 < 16) ? 0 : (w0 - 2) / 14;
    int jmax0 = (w0 + 63) / 14; if (jmax0 > 8) jmax0 = 8;
    float* xf = (float*)(lds + 16384);
    char* wch = lds + 16384;
    for (int e = tid; e < 8320; e += 256) xf[e] = 0.f;
    __syncthreads();
    {
        int c = tid >> 1, half = tid & 1;
        for (int ii = imin; ii <= imax; ++ii) {
            int trow = h - ii * 14;
            for (int jj = jmin0; jj <= jmax0; ++jj) {
                int s = jj * 14 - w0 + half * 8;
                if (s >= 0 && s <= 56) {
                    const bf16* tp = t2 + (size_t)((b * 9 + ii) * 9 + jj) * 32768
                                   + (size_t)c * 256 + trow * 16 + half * 8;
                    union { uint4 u; bf16 hh[8]; } qv;
                    qv.u = *(const uint4*)tp;
                    float* xr = xf + c * 65 + s;
                    #pragma unroll
                    for (int k2 = 0; k2 < 8; ++k2) xr[k2] += b2f(qv.hh[k2]);
                }
            }
        }
    }
    __syncthreads();
    for (int e = tid; e < 2048; e += 256) {
        int c = e >> 4, qd = e & 15;
        int i0 = qd * 4;
        union { bf16 hh[4]; uint2 u; } t4;
        #pragma unroll
        for (int k2 = 0; k2 < 4; ++k2) {
            int i = i0 + k2;
            int wp = w0 + i;
            int jmn = (wp < 16) ? 0 : (wp - 2) / 14; int jmx = wp / 14; if (jmx > 8) jmx = 8;
            float inv = 1.0f / (float)((imax - imin + 1) * (jmx - jmn + 1));
            float val = xf[c * 65 + i] * inv;
            xf[c * 65 + i] = val;
            t4.hh[k2] = f2b(val);
        }
        *(uint2*)(x2w + (size_t)(b * C_ + c) * N_ + nb + i0) = t4.u;
    }
    __syncthreads();
    {
        int i = tid & 63, r = tid >> 6;
        float s = 0.f, ss = 0.f;
        for (int cc = r * 32; cc < r * 32 + 32; ++cc) { float vv = xf[cc * 65 + i]; s += vv; ss += vv * vv; }
        red2[r][i] = s; red2[4 + r][i] = ss;
    }
    __syncthreads();
    if (tid < 64) {
        float s = red2[0][tid] + red2[1][tid] + red2[2][tid] + red2[3][tid];
        float ss = red2[4][tid] + red2[5][tid] + red2[6][tid] + red2[7][tid];
        float mu = s * (1.f / 128.f); float var = ss * (1.f / 128.f) - mu * mu;
        mu_l[tid] = mu; rs_l[tid] = rsqrtf(var + 1e-6f);
    }
    __syncthreads();
    {
        int c = tid & 127;
        float g = lng[c], be = lnb[c];
        for (int e = tid; e < 8192; e += 256) {
            int i = e >> 7;
            float val = (xf[c * 65 + i] - mu_l[i]) * rs_l[i] * g + be;
            *(bf16*)(lds + i * 256 + ((2 * c) ^ ((i & 7) << 4))) = f2b(val);
        }
    }
    __syncthreads();
    bf16x8 afr[4];
    {
        int row = w * 16 + l15;
        #pragma unroll
        for (int cc = 0; cc < 4; ++cc) {
            int cbyt = cc * 64 + lhi * 16;
            afr[cc] = *(const bf16x8*)(lds + row * 256 + (cbyt ^ ((row & 7) << 4)));
        }
    }
    for (int p = 0; p < 2; ++p) {
        __syncthreads();
        for (int e = tid; e < 2048; e += 256) {
            int row = e >> 4, slot = e & 15;
            uint4 val = *(const uint4*)((const char*)wt1 + (size_t)(p * 128 + row) * 256 + slot * 16);
            *(uint4*)(wch + row * 256 + ((slot * 16) ^ ((row & 7) << 4))) = val;
        }
        __syncthreads();
        f32x4 acc[8];
        #pragma unroll
        for (int t = 0; t < 8; ++t) acc[t] = (f32x4){0.f, 0.f, 0.f, 0.f};
        #pragma unroll
        for (int ot = 0; ot < 8; ++ot) {
            int row = ot * 16 + l15;
            #pragma unroll
            for (int cc = 0; cc < 4; ++cc) {
                int cbyt = cc * 64 + lhi * 16;
                bf16x8 bfr = *(const bf16x8*)(wch + row * 256 + (cbyt ^ ((row & 7) << 4)));
                acc[ot] = __builtin_amdgcn_mfma_f32_16x16x32_bf16(afr[cc], bfr, acc[ot], 0, 0, 0);
            }
        }
        int n0 = nb + w * 16 + lhi * 4;
        #pragma unroll
        for (int ot = 0; ot < 8; ++ot) {
            int o = p * 128 + ot * 16 + l15;
            float bi = b1[o];
            union { bf16 h[4]; uint2 u; } t4;
            #pragma unroll
            for (int r = 0; r < 4; ++r) t4.h[r] = f2b(gelu_f(acc[ot][r] + bi));
            *(uint2*)(h1 + (size_t)(b * 256 + o) * N_ + n0) = t4.u;
        }
    }
}

// ---------------- K9: h2 = h1 + dwconv5x5(h1) + dw_b  full-plane LDS (bf16) ----------------
__global__ __launch_bounds__(256) void k_dw5p(const bf16* __restrict__ h1, const float* __restrict__ wdw,
                                              const float* __restrict__ bdw, bf16* __restrict__ h2) {
    __shared__ __align__(16) char tile[38016];     // 132 rows x 288B
    int tid = threadIdx.x;
    int bid = blockIdx.x;                          // 2048 = 8b * 256ch
    int ch = bid & 255, b = bid >> 8;
    const bf16* p = h1 + (size_t)(b * 256 + ch) * N_;
    for (int e = tid; e < 2376; e += 256) *(uint4*)(tile + e * 16) = (uint4){0, 0, 0, 0};
    __syncthreads();
    for (int e = tid; e < 2048; e += 256) {
        int gr = e >> 4, slot = e & 15;
        uint4 val = *(const uint4*)(p + gr * 128 + slot * 8);
        *(uint4*)(tile + (gr + 2) * 288 + 16 + slot * 16) = val;
    }
    float kw[25];
    #pragma unroll
    for (int j = 0; j < 25; ++j) kw[j] = wdw[ch * 25 + j];
    float bi = bdw[ch];
    __syncthreads();
    int hg = tid >> 4, wg = tid & 15;
    int h0 = hg * 8;
    float ring[5][12];
    #pragma unroll
    for (int j = 0; j < 4; ++j) load_row12(tile, h0 + j, wg, ring[j]);
    bf16* op = h2 + (size_t)(b * 256 + ch) * N_;
    #pragma unroll
    for (int rr = 0; rr < 8; ++rr) {
        load_row12(tile, h0 + rr + 4, wg, ring[(rr + 4) % 5]);
        float acc[8];
        #pragma unroll
        for (int ow = 0; ow < 8; ++ow) acc[ow] = bi;
        #pragma unroll
        for (int ky = 0; ky < 5; ++ky) {
            const float* e = ring[(rr + ky) % 5];
            #pragma unroll
            for (int ow = 0; ow < 8; ++ow) {
                #pragma unroll
                for (int kx = 0; kx < 5; ++kx)
                    acc[ow] = fmaf(kw[ky * 5 + kx], e[ow + kx], acc[ow]);
            }
        }
        {
            const float* e = ring[(rr + 2) % 5];
            #pragma unroll
            for (int ow = 0; ow < 8; ++ow) acc[ow] += e[ow + 2];
        }
        union { bf16 h[8]; uint4 u; } outv;
        #pragma unroll
        for (int ow = 0; ow < 8; ++ow) outv.h[ow] = f2b(acc[ow]);
        *(uint4*)(op + (h0 + rr) * 128 + wg * 8) = outv.u;
    }
}

// ---------------- K10: fc2 MFMA GEMM (K=256) + bias + residual -> d_out (fp32) ----------------
__global__ __launch_bounds__(256) void k_fc2_mfma(const bf16* __restrict__ h2, const bf16* __restrict__ wt2,
                                                  const float* __restrict__ b2, const bf16* __restrict__ x2,
                                                  float* __restrict__ out) {
    __shared__ __align__(16) char lds[65536];   // [0,32K): A tile [64][512B]; [32K,64K): W half
    int tid = threadIdx.x;
    int lane = tid & 63, w = tid >> 6;
    int l15 = lane & 15, lhi = lane >> 4;
    int gtok = blockIdx.x * 64; int b = gtok >> 14; int nb = gtok & (N_ - 1);
    char* wch = lds + 32768;
    for (int e = tid; e < 16384; e += 256) {
        int c = e >> 6, i = e & 63;
        bf16 val = h2[(size_t)(b * 256 + c) * N_ + nb + i];
        *(bf16*)(lds + i * 512 + ((2 * c) ^ ((i & 7) << 4))) = val;
    }
    __syncthreads();
    bf16x8 afr[8];
    {
        int row = w * 16 + l15;
        #pragma unroll
        for (int cc = 0; cc < 8; ++cc) {
            int cbyt = cc * 64 + lhi * 16;
            afr[cc] = *(const bf16x8*)(lds + row * 512 + (cbyt ^ ((row & 7) << 4)));
        }
    }
    f32x4 acc[8];
    #pragma unroll
    for (int t = 0; t < 8; ++t) acc[t] = (f32x4){0.f, 0.f, 0.f, 0.f};
    for (int kh = 0; kh < 2; ++kh) {
        __syncthreads();
        for (int e = tid; e < 2048; e += 256) {
            int row = e >> 4, slot = e & 15;
            uint4 val = *(const uint4*)((const char*)wt2 + (size_t)row * 512 + kh * 256 + slot * 16);
            *(uint4*)(wch + row * 256 + ((slot * 16) ^ ((row & 7) << 4))) = val;
        }
        __syncthreads();
        #pragma unroll
        for (int ot = 0; ot < 8; ++ot) {
            int row = ot * 16 + l15;
            #pragma unroll
            for (int cc = 0; cc < 4; ++cc) {
                int cbyt = cc * 64 + lhi * 16;
                bf16x8 bfr = *(const bf16x8*)(wch + row * 256 + (cbyt ^ ((row & 7) << 4)));
                acc[ot] = __builtin_amdgcn_mfma_f32_16x16x32_bf16(afr[kh * 4 + cc], bfr, acc[ot], 0, 0, 0);
            }
        }
    }
    int n0 = nb + w * 16 + lhi * 4;
    #pragma unroll
    for (int ot = 0; ot < 8; ++ot) {
        int o = ot * 16 + l15;
        size_t obase = (size_t)(b * C_ + o) * N_ + n0;
        float bi = b2[o];
        union { uint2 u; bf16 h[4]; } xr;
        xr.u = *(const uint2*)(x2 + obase);
        float4 r4;
        r4.x = acc[ot][0] + bi + b2f(xr.h[0]);
        r4.y = acc[ot][1] + bi + b2f(xr.h[1]);
        r4.z = acc[ot][2] + bi + b2f(xr.h[2]);
        r4.w = acc[ot][3] + bi + b2f(xr.h[3]);
        *(float4*)(out + obase) = r4;
    }
}

extern "C" void kernel_launch(void* const* d_in, const int* in_sizes, int n_in,
                              void* d_out, int out_size, void* d_ws, size_t ws_size,
                              hipStream_t stream) {
    const float* x         = (const float*)d_in[0];
    const float* lth_dw_w  = (const float*)d_in[2];
    const float* lth_pw_w  = (const float*)d_in[3];
    const float* lth_pw_b  = (const float*)d_in[4];
    const float* lth_gate_w= (const float*)d_in[5];
    const float* lth_gate_b= (const float*)d_in[6];
    const float* lth_scale = (const float*)d_in[7];
    const float* ln1_g     = (const float*)d_in[8];
    const float* ln1_b     = (const float*)d_in[9];
    const float* ln2_g     = (const float*)d_in[10];
    const float* ln2_b     = (const float*)d_in[11];
    const float* qkv_w     = (const float*)d_in[12];
    const float* gate_w    = (const float*)d_in[13];
    const float* gate_b    = (const float*)d_in[14];
    const float* proj_w    = (const float*)d_in[15];
    const float* pe_w      = (const float*)d_in[16];
    const float* pe_b      = (const float*)d_in[17];
    const float* fc1_w     = (const float*)d_in[18];
    const float* fc1_b     = (const float*)d_in[19];
    const float* dw_w      = (const float*)d_in[20];
    const float* dw_b      = (const float*)d_in[21];
    const float* fc2_w     = (const float*)d_in[22];
    const float* fc2_b     = (const float*)d_in[23];

    // Slab plan (bytes), peak ~234.5 MiB (proven R13):
    //  A: x1 ; h2 spans A+B (x1/o dead by dw5p)
    //  B: sg -> o (read-only through proj now)
    //  C: q -> x2 (q dead after proj; x2 written by fc1ln)
    //  D: hf -> k -> t2 (t2 live through fc1ln)
    //  E: g -> v ; h1 spans E+F
    //  F: z
    //  G: wt(32K) H: wqkv(128K) I: wt1(64K) wt2(64K) wpw(32K)
    char* ws = (char*)d_ws;
    constexpr size_t SZ_X = 33554432;    // bf16, 16,777,216 elems
    constexpr size_t SZ_W = 42467328;    // bf16, 21,233,664 elems
    constexpr size_t OFF_A = 0;
    constexpr size_t OFF_B = OFF_A + SZ_X;
    constexpr size_t OFF_C = OFF_B + SZ_W;
    constexpr size_t OFF_D = OFF_C + SZ_W;
    constexpr size_t OFF_E = OFF_D + SZ_W;
    constexpr size_t OFF_F = OFF_E + SZ_W;
    constexpr size_t OFF_G = OFF_F + SZ_W;
    constexpr size_t OFF_H = OFF_G + 32768;
    constexpr size_t OFF_I = OFF_H + 131072;

    bf16*  x1  = (bf16*)(ws + OFF_A);
    bf16*  h2  = (bf16*)(ws + OFF_A);   // spans A+B
    float* sg  = (float*)(ws + OFF_B + 16777216);
    bf16*  o   = (bf16*)(ws + OFF_B);
    bf16*  q   = (bf16*)(ws + OFF_C);
    bf16*  x2  = (bf16*)(ws + OFF_C);
    bf16*  hf  = (bf16*)(ws + OFF_D);
    bf16*  k   = (bf16*)(ws + OFF_D);
    bf16*  t2  = (bf16*)(ws + OFF_D);
    bf16*  g   = (bf16*)(ws + OFF_E);
    bf16*  v   = (bf16*)(ws + OFF_E);
    bf16*  h1  = (bf16*)(ws + OFF_E);   // spans E+F
    bf16*  z   = (bf16*)(ws + OFF_F);
    bf16*  wt  = (bf16*)(ws + OFF_G);
    bf16*  wqkv= (bf16*)(ws + OFF_H);
    bf16*  wt1 = (bf16*)(ws + OFF_I);
    bf16*  wt2 = (bf16*)(ws + OFF_I + 65536);
    bf16*  wpw = (bf16*)(ws + OFF_I + 131072);

    k_wprep   <<<640,   256, 0, stream>>>(proj_w, qkv_w, gate_w, fc1_w, fc2_w, lth_pw_w,
                                          wt, wqkv, wt1, wt2, wpw);
    k_hf2     <<<8192,  256, 0, stream>>>(x, hf);
    k_sgate   <<<512,   256, 0, stream>>>(hf, lth_gate_w, lth_gate_b, sg);
    k_dw3p    <<<1024,  256, 0, stream>>>(hf, lth_dw_w, g);
    k_pw_mfma <<<2048,  256, 0, stream>>>(g, wpw, lth_pw_b, x, lth_scale, sg, x1);
    k_qkv_mfma<<<2592,  256, 0, stream>>>(x1, ln1_g, ln1_b, wqkv, gate_b, q, k, v, z);
    k_attn_mfma<<<2592, 256, 0, stream>>>(q, k, v, o);
    k_proj    <<<2592,  256, 0, stream>>>(o, q, z, wt, x1, pe_w, pe_b, t2);
    k_fc1ln   <<<2048,  256, 0, stream>>>(t2, ln2_g, ln2_b, wt1, fc1_b, h1, x2);
    k_dw5p    <<<2048,  256, 0, stream>>>(h1, dw_w, dw_b, h2);
    k_fc2_mfma<<<2048,  256, 0, stream>>>(h2, wt2, fc2_b, x2, (float*)d_out);
}

// Round 20
// 505.633 us; speedup vs baseline: 1.0477x; 1.0289x over previous
//
#include <hip/hip_runtime.h>
#include <hip/hip_bf16.h>
#include <math.h>

typedef __hip_bfloat16 bf16;
typedef __attribute__((ext_vector_type(8))) short bf16x8;
typedef __attribute__((ext_vector_type(4))) float f32x4;

static constexpr int B_ = 8, C_ = 128, H_ = 128, W_ = 128;
static constexpr int N_ = H_ * W_;          // 16384
static constexpr int NWIN = 648;            // B * 9 * 9

__device__ __forceinline__ float b2f(bf16 v) { return __bfloat162float(v); }
__device__ __forceinline__ bf16 f2b(float v) { return __float2bfloat16(v); }

// erf-free exact-GELU: A&S 7.1.26 rational erf approx (|err|<=1.5e-7), pure FMA + v_exp.
__device__ __forceinline__ float gelu_f(float x) {
    float xs = x * 0.70710678118654752f;
    float ax = fabsf(xs);
    float t = 1.0f / fmaf(0.3275911f, ax, 1.0f);
    float poly = t * fmaf(t, fmaf(t, fmaf(t, fmaf(t, 1.061405429f, -1.453152027f), 1.421413741f), -0.284496736f), 0.254829592f);
    float erf_ax = fmaf(-poly, __expf(-ax * ax), 1.0f);
    float erfv = copysignf(erf_ax, xs);
    return 0.5f * x * (1.0f + erfv);
}

// 12-wide row extraction from padded plane tile (row bytes: [0,16) left pad, [16,272) cols, [272,288) right pad)
__device__ __forceinline__ void load_row12(const char* tile, int a, int wg, float* dst) {
    int base = a * 288 + wg * 16;
    union { uint4 u; bf16 hh[8]; } c0, c1, c2;
    c0.u = *(const uint4*)(tile + base);
    c1.u = *(const uint4*)(tile + base + 16);
    c2.u = *(const uint4*)(tile + base + 32);
    dst[0] = b2f(c0.hh[6]); dst[1] = b2f(c0.hh[7]);
    #pragma unroll
    for (int j = 0; j < 8; ++j) dst[2 + j] = b2f(c1.hh[j]);
    dst[10] = b2f(c2.hh[0]); dst[11] = b2f(c2.hh[1]);
}

// ---------------- K0: all weight preps merged (one-off) ----------------
__global__ __launch_bounds__(256) void k_wprep(const float* __restrict__ projw, const float* __restrict__ qkvw,
                                               const float* __restrict__ gatew, const float* __restrict__ w1,
                                               const float* __restrict__ w2, const float* __restrict__ pww,
                                               bf16* __restrict__ wt, bf16* __restrict__ wqkv,
                                               bf16* __restrict__ wt1, bf16* __restrict__ wt2,
                                               bf16* __restrict__ wpw) {
    int idx = blockIdx.x * 256 + threadIdx.x;    // 163840
    if (idx < 16384) {
        int o = idx >> 7, c = idx & 127;
        wt[idx] = f2b(projw[c * 128 + o]);
    } else if (idx < 81920) {
        int i = idx - 16384; int o = i >> 7, c = i & 127;
        wqkv[i] = f2b((o < 384) ? qkvw[c * 384 + o] : gatew[c * 128 + (o - 384)]);
    } else if (idx < 114688) {
        int i = idx - 81920; int o = i >> 7, c = i & 127;
        wt1[i] = f2b(w1[c * 256 + o]);
    } else if (idx < 147456) {
        int i = idx - 114688; int o = i >> 8, c = i & 255;
        wt2[i] = f2b(w2[c * 128 + o]);
    } else {
        int i = idx - 147456;
        wpw[i] = f2b(pww[i]);
    }
}

// ---------------- K1: fused 2x2-pool + bilinear-up + hf = x - up (bf16 out) ----------------
__global__ __launch_bounds__(256) void k_hf2(const float* __restrict__ x, bf16* __restrict__ hf) {
    __shared__ float lowt[10][64];
    int tid = threadIdx.x;
    int bid = blockIdx.x;                       // 8192 = 8b * 128c * 8ht
    int ht = bid & 7, c = (bid >> 3) & 127, b = bid >> 10;
    const float* xp = x + (size_t)(b * C_ + c) * N_;
    int h0 = ht * 16;
    int lo0 = (h0 >> 1) - 1;
    for (int e = tid; e < 640; e += 256) {
        int lr = e >> 6, jc = e & 63;
        int j = lo0 + lr; j = j < 0 ? 0 : (j > 63 ? 63 : j);
        const float* pr = xp + (2 * j) * W_ + 2 * jc;
        lowt[lr][jc] = (pr[0] + pr[1] + pr[W_] + pr[W_ + 1]) * 0.25f;
    }
    __syncthreads();
    int hl = tid >> 4, wg = tid & 15;
    int h = h0 + hl;
    int jh = h >> 1;
    int j0, j1; float wh0, wh1;
    if (h & 1) { j0 = jh; j1 = jh + 1 > 63 ? 63 : jh + 1; wh0 = 0.75f; wh1 = 0.25f; }
    else       { j0 = jh - 1 < 0 ? 0 : jh - 1; j1 = jh;   wh0 = 0.25f; wh1 = 0.75f; }
    int l0 = j0 - lo0, l1 = j1 - lo0;
    float4 xa = *(const float4*)(xp + h * W_ + wg * 8);
    float4 xb = *(const float4*)(xp + h * W_ + wg * 8 + 4);
    float xv[8] = {xa.x, xa.y, xa.z, xa.w, xb.x, xb.y, xb.z, xb.w};
    union { bf16 hh[8]; uint4 u; } outv;
    #pragma unroll
    for (int k2 = 0; k2 < 8; ++k2) {
        int w = wg * 8 + k2;
        int jw = w >> 1;
        int w0, w1; float ww0, ww1;
        if (w & 1) { w0 = jw; w1 = jw + 1 > 63 ? 63 : jw + 1; ww0 = 0.75f; ww1 = 0.25f; }
        else       { w0 = jw - 1 < 0 ? 0 : jw - 1; w1 = jw;   ww0 = 0.25f; ww1 = 0.75f; }
        float up = wh0 * (ww0 * lowt[l0][w0] + ww1 * lowt[l0][w1])
                 + wh1 * (ww0 * lowt[l1][w0] + ww1 * lowt[l1][w1]);
        outv.hh[k2] = f2b(xv[k2] - up);
    }
    *(uint4*)(hf + (size_t)(b * C_ + c) * N_ + h * W_ + wg * 8) = outv.u;
}

// ---------------- K2: sgate (fp32 out) ----------------
__global__ __launch_bounds__(256) void k_sgate(const bf16* __restrict__ hf, const float* __restrict__ gw,
                                               const float* __restrict__ gb, float* __restrict__ sg) {
    int idx = blockIdx.x * 256 + threadIdx.x;       // 131072
    int n = idx & (N_ - 1); int b = idx >> 14;
    const bf16* p = hf + (size_t)b * C_ * N_ + n;
    float s = 0.f;
    for (int c = 0; c < C_; ++c) s += gw[c] * fabsf(b2f(p[(size_t)c * N_]));
    s += gb[0];
    sg[idx] = 1.0f / (1.0f + __expf(-s));
}

// ---------------- K3: g = gelu(dwconv3x3 dil2) full-plane LDS (bf16) ----------------
__global__ __launch_bounds__(256) void k_dw3p(const bf16* __restrict__ hf, const float* __restrict__ wdw,
                                              bf16* __restrict__ g) {
    __shared__ __align__(16) char tile[38016];     // 132 rows x 288B (8-col zero pads each side)
    int tid = threadIdx.x;
    int bid = blockIdx.x;                          // 1024 = 8b * 128c
    int ch = bid & 127, b = bid >> 7;
    const bf16* p = hf + (size_t)(b * C_ + ch) * N_;
    for (int e = tid; e < 2376; e += 256) *(uint4*)(tile + e * 16) = (uint4){0, 0, 0, 0};
    __syncthreads();
    for (int e = tid; e < 2048; e += 256) {
        int gr = e >> 4, slot = e & 15;
        uint4 val = *(const uint4*)(p + gr * 128 + slot * 8);
        *(uint4*)(tile + (gr + 2) * 288 + 16 + slot * 16) = val;
    }
    float kw[9];
    #pragma unroll
    for (int j = 0; j < 9; ++j) kw[j] = wdw[ch * 9 + j];
    __syncthreads();
    int hg = tid >> 4, wg = tid & 15;
    int h0 = hg * 8;
    float ring[5][12];
    #pragma unroll
    for (int j = 0; j < 4; ++j) load_row12(tile, h0 + j, wg, ring[j]);
    bf16* op = g + (size_t)(b * C_ + ch) * N_;
    #pragma unroll
    for (int rr = 0; rr < 8; ++rr) {
        load_row12(tile, h0 + rr + 4, wg, ring[(rr + 4) % 5]);
        float acc[8] = {};
        #pragma unroll
        for (int ky = 0; ky < 3; ++ky) {
            const float* e = ring[(rr + 2 * ky) % 5];
            #pragma unroll
            for (int ow = 0; ow < 8; ++ow) {
                acc[ow] = fmaf(kw[ky * 3 + 0], e[ow], acc[ow]);
                acc[ow] = fmaf(kw[ky * 3 + 1], e[ow + 2], acc[ow]);
                acc[ow] = fmaf(kw[ky * 3 + 2], e[ow + 4], acc[ow]);
            }
        }
        union { bf16 h[8]; uint4 u; } outv;
        #pragma unroll
        for (int ow = 0; ow < 8; ++ow) outv.h[ow] = f2b(gelu_f(acc[ow]));
        *(uint4*)(op + (h0 + rr) * 128 + wg * 8) = outv.u;
    }
}

// ---------------- K4: pw MFMA GEMM + LTH epilogue -> x1 (bf16) ----------------
__global__ __launch_bounds__(256) void k_pw_mfma(const bf16* __restrict__ g, const bf16* __restrict__ wpw,
                                                 const float* __restrict__ pwb, const float* __restrict__ x,
                                                 const float* __restrict__ scale, const float* __restrict__ sg,
                                                 bf16* __restrict__ x1) {
    __shared__ __align__(16) char lds[49152];   // [0,16K): A tile; [16K,48K): W
    int tid = threadIdx.x;
    int lane = tid & 63, w = tid >> 6;
    int l15 = lane & 15, lhi = lane >> 4;
    int gtok = blockIdx.x * 64; int b = gtok >> 14; int nb = gtok & (N_ - 1);
    char* wch = lds + 16384;
    for (int e = tid; e < 8192; e += 256) {
        int c = e >> 6, i = e & 63;
        bf16 val = g[(size_t)(b * C_ + c) * N_ + nb + i];
        *(bf16*)(lds + i * 256 + ((2 * c) ^ ((i & 7) << 4))) = val;
    }
    for (int e = tid; e < 2048; e += 256) {
        int row = e >> 4, slot = e & 15;
        uint4 val = *(const uint4*)((const char*)wpw + row * 256 + slot * 16);
        *(uint4*)(wch + row * 256 + ((slot * 16) ^ ((row & 7) << 4))) = val;
    }
    __syncthreads();
    bf16x8 afr[4];
    {
        int row = w * 16 + l15;
        #pragma unroll
        for (int cc = 0; cc < 4; ++cc) {
            int cbyt = cc * 64 + lhi * 16;
            afr[cc] = *(const bf16x8*)(lds + row * 256 + (cbyt ^ ((row & 7) << 4)));
        }
    }
    f32x4 acc[8];
    #pragma unroll
    for (int t = 0; t < 8; ++t) acc[t] = (f32x4){0.f, 0.f, 0.f, 0.f};
    #pragma unroll
    for (int ot = 0; ot < 8; ++ot) {
        int row = ot * 16 + l15;
        #pragma unroll
        for (int cc = 0; cc < 4; ++cc) {
            int cbyt = cc * 64 + lhi * 16;
            bf16x8 bfr = *(const bf16x8*)(wch + row * 256 + (cbyt ^ ((row & 7) << 4)));
            acc[ot] = __builtin_amdgcn_mfma_f32_16x16x32_bf16(afr[cc], bfr, acc[ot], 0, 0, 0);
        }
    }
    int n0 = nb + w * 16 + lhi * 4;
    float4 sg4 = *(const float4*)&sg[b * N_ + n0];
    #pragma unroll
    for (int ot = 0; ot < 8; ++ot) {
        int o = ot * 16 + l15;
        size_t obase = (size_t)(b * C_ + o) * N_ + n0;
        float4 x4 = *(const float4*)&x[obase];
        float sc = scale[o], bi = pwb[o];
        union { bf16 h[4]; uint2 u; } t4;
        t4.h[0] = f2b(x4.x + sc * (acc[ot][0] + bi) * sg4.x);
        t4.h[1] = f2b(x4.y + sc * (acc[ot][1] + bi) * sg4.y);
        t4.h[2] = f2b(x4.z + sc * (acc[ot][2] + bi) * sg4.z);
        t4.h[3] = f2b(x4.w + sc * (acc[ot][3] + bi) * sg4.w);
        *(uint2*)(x1 + obase) = t4.u;
    }
}

// ---------------- K5: LN1 + qkv/gate MFMA GEMM -> q,k,z [tok][c]; v [c][tok] ----------------
// R14 form: proven deterministic across graph replays (validated R14/R17).
__global__ __launch_bounds__(256) void k_qkv_mfma(const bf16* __restrict__ x1, const float* __restrict__ lng,
                                                  const float* __restrict__ lnb, const bf16* __restrict__ wall,
                                                  const float* __restrict__ gateb,
                                                  bf16* __restrict__ q, bf16* __restrict__ k,
                                                  bf16* __restrict__ v, bf16* __restrict__ z) {
    __shared__ __align__(16) char lds[49664];   // [0,16K): y bf16 swizzled; [16K,...): xf fp32 [128][65] -> w chunk
    __shared__ float red2[8][64];
    __shared__ float mu_l[64], rs_l[64];
    int tid = threadIdx.x;
    int lane = tid & 63, w = tid >> 6;
    int l15 = lane & 15, lhi = lane >> 4;
    int win = blockIdx.x >> 2; int qbase = (blockIdx.x & 3) * 64;
    int b = win / 81; int r0 = win % 81; int top = (r0 / 9) * 14, left = (r0 % 9) * 14;
    float* xf = (float*)(lds + 16384);           // [128][65] fp32
    char* wchunk = lds + 16384;                  // same region, after xf dies
    for (int e = tid; e < 8192; e += 256) {
        int c = e >> 6, i = e & 63; int tok = qbase + i; int p = tok >> 4, qq = tok & 15;
        xf[c * 65 + i] = b2f(x1[(size_t)(b * C_ + c) * N_ + (top + p) * W_ + (left + qq)]);
    }
    __syncthreads();
    {
        int i = tid & 63, r = tid >> 6;
        float s = 0.f, ss = 0.f;
        for (int cc = r * 32; cc < r * 32 + 32; ++cc) { float vv = xf[cc * 65 + i]; s += vv; ss += vv * vv; }
        red2[r][i] = s; red2[4 + r][i] = ss;
    }
    __syncthreads();
    if (tid < 64) {
        float s = red2[0][tid] + red2[1][tid] + red2[2][tid] + red2[3][tid];
        float ss = red2[4][tid] + red2[5][tid] + red2[6][tid] + red2[7][tid];
        float mu = s * (1.f / 128.f); float var = ss * (1.f / 128.f) - mu * mu;
        mu_l[tid] = mu; rs_l[tid] = rsqrtf(var + 1e-6f);
    }
    __syncthreads();
    {
        int c = tid & 127;
        float g = lng[c], be = lnb[c];
        for (int e = tid; e < 8192; e += 256) {
            int i = e >> 7;
            float val = (xf[c * 65 + i] - mu_l[i]) * rs_l[i] * g + be;
            *(bf16*)(lds + i * 256 + ((2 * c) ^ ((i & 7) << 4))) = f2b(val);
        }
    }
    __syncthreads();
    bf16x8 afr[4];
    {
        int row = w * 16 + l15;
        #pragma unroll
        for (int cc = 0; cc < 4; ++cc) {
            int cbyt = cc * 64 + lhi * 16;
            afr[cc] = *(const bf16x8*)(lds + row * 256 + (cbyt ^ ((row & 7) << 4)));
        }
    }
    for (int pass = 0; pass < 4; ++pass) {
        __syncthreads();
        for (int e = tid; e < 2048; e += 256) {
            int row = e >> 4, slot = e & 15;
            uint4 val = *(const uint4*)((const char*)wall + (size_t)(pass * 128 + row) * 256 + slot * 16);
            *(uint4*)(wchunk + row * 256 + ((slot * 16) ^ ((row & 7) << 4))) = val;
        }
        __syncthreads();
        f32x4 acc[8];
        #pragma unroll
        for (int t = 0; t < 8; ++t) acc[t] = (f32x4){0.f, 0.f, 0.f, 0.f};
        #pragma unroll
        for (int ot = 0; ot < 8; ++ot) {
            int row = ot * 16 + l15;
            #pragma unroll
            for (int cc = 0; cc < 4; ++cc) {
                int cbyt = cc * 64 + lhi * 16;
                bf16x8 bfr = *(const bf16x8*)(wchunk + row * 256 + (cbyt ^ ((row & 7) << 4)));
                acc[ot] = __builtin_amdgcn_mfma_f32_16x16x32_bf16(afr[cc], bfr, acc[ot], 0, 0, 0);
            }
        }
        if (pass != 2) {
            bf16* outp = (pass == 0) ? q : (pass == 1) ? k : z;   // [win][tok][c]
            bool gel = (pass == 3);
            #pragma unroll
            for (int ot = 0; ot < 8; ++ot) {
                int o = ot * 16 + l15;
                float gb = gel ? gateb[o] : 0.f;
                #pragma unroll
                for (int r = 0; r < 4; ++r) {
                    int gtok = qbase + w * 16 + lhi * 4 + r;
                    float vv = acc[ot][r];
                    outp[((size_t)win * 256 + gtok) * 128 + o] = gel ? f2b(gelu_f(vv + gb)) : f2b(vv);
                }
            }
        } else {                                  // v: [win][c][tok]
            #pragma unroll
            for (int ot = 0; ot < 8; ++ot) {
                int o = ot * 16 + l15;
                union { bf16 h[4]; uint2 u; } t4;
                #pragma unroll
                for (int r = 0; r < 4; ++r) t4.h[r] = f2b(acc[ot][r]);
                *(uint2*)(v + (size_t)win * 32768 + (size_t)o * 256 + qbase + w * 16 + lhi * 4) = t4.u;
            }
        }
    }
}

// ---------------- K6: MFMA attention core: softmax(QK^T*scale)V -> o [win][tok][c] ----------------
// R15 (validated): XCD-aware block map (4 quarters of a window share an XCD -> k/v L2 reuse);
// PV operand swap -> packed uint2 o-stores.
__global__ __launch_bounds__(256) void k_attn_mfma(const bf16* __restrict__ qb, const bf16* __restrict__ kb,
                                                   const bf16* __restrict__ vb, bf16* __restrict__ ob) {
    __shared__ __align__(16) char lds[49152];   // [0,32K): q (16K) then P (32K); [32K,48K): K/V chunk
    int tid = threadIdx.x;
    int lane = tid & 63, w = tid >> 6;
    int l15 = lane & 15, lhi = lane >> 4;
    int xcd = blockIdx.x & 7, ixd = blockIdx.x >> 3;   // 648 windows = 8 XCDs x 81
    int win = xcd * 81 + (ixd >> 2);
    int qbase = (ixd & 3) * 64;
    const bf16* qg = qb + ((size_t)win * 256 + qbase) * 128;   // [64][128]
    const bf16* kg = kb + (size_t)win * 256 * 128;             // [256][128]
    const bf16* vg = vb + (size_t)win * 128 * 256;             // [128][256]
    char* chunk = lds + 32768;
    for (int e = tid; e < 1024; e += 256) {
        int row = e >> 4, slot = e & 15;
        uint4 val = *(const uint4*)((const char*)qg + row * 256 + slot * 16);
        *(uint4*)(lds + row * 256 + ((slot * 16) ^ ((row & 7) << 4))) = val;
    }
    __syncthreads();
    bf16x8 afr[4];
    {
        int row = w * 16 + l15;
        #pragma unroll
        for (int cc = 0; cc < 4; ++cc) {
            int cb = cc * 64 + lhi * 16;
            afr[cc] = *(const bf16x8*)(lds + row * 256 + (cb ^ ((row & 7) << 4)));
        }
    }
    f32x4 acc[16];
    #pragma unroll
    for (int t = 0; t < 16; ++t) acc[t] = (f32x4){0.f, 0.f, 0.f, 0.f};
    for (int kc = 0; kc < 4; ++kc) {
        __syncthreads();
        for (int e = tid; e < 1024; e += 256) {
            int row = e >> 4, slot = e & 15;
            uint4 val = *(const uint4*)((const char*)kg + (size_t)(kc * 64 + row) * 256 + slot * 16);
            *(uint4*)(chunk + row * 256 + ((slot * 16) ^ ((row & 7) << 4))) = val;
        }
        __syncthreads();
        #pragma unroll
        for (int t = 0; t < 4; ++t) {
            int row = t * 16 + l15;
            #pragma unroll
            for (int cc = 0; cc < 4; ++cc) {
                int cb = cc * 64 + lhi * 16;
                bf16x8 bfr = *(const bf16x8*)(chunk + row * 256 + (cb ^ ((row & 7) << 4)));
                acc[kc * 4 + t] = __builtin_amdgcn_mfma_f32_16x16x32_bf16(afr[cc], bfr, acc[kc * 4 + t], 0, 0, 0);
            }
        }
    }
    const float sm_scale = 0.08838834764831845f;   // 128^-0.5
    #pragma unroll
    for (int r = 0; r < 4; ++r) {
        float m = -1e30f;
        #pragma unroll
        for (int t = 0; t < 16; ++t) m = fmaxf(m, acc[t][r]);
        #pragma unroll
        for (int d2 = 1; d2 < 16; d2 <<= 1) m = fmaxf(m, __shfl_xor(m, d2, 64));
        float ssum = 0.f;
        #pragma unroll
        for (int t = 0; t < 16; ++t) { float p = __expf((acc[t][r] - m) * sm_scale); acc[t][r] = p; ssum += p; }
        #pragma unroll
        for (int d2 = 1; d2 < 16; d2 <<= 1) ssum += __shfl_xor(ssum, d2, 64);
        float inv = 1.f / ssum;
        #pragma unroll
        for (int t = 0; t < 16; ++t) acc[t][r] *= inv;
    }
    #pragma unroll
    for (int t = 0; t < 16; ++t) {
        #pragma unroll
        for (int r = 0; r < 4; ++r) {
            int row = w * 16 + lhi * 4 + r;
            int cb = (t * 16 + l15) * 2;
            *(bf16*)(lds + row * 512 + (cb ^ ((row & 7) << 4))) = f2b(acc[t][r]);
        }
    }
    f32x4 oacc[8];
    #pragma unroll
    for (int t = 0; t < 8; ++t) oacc[t] = (f32x4){0.f, 0.f, 0.f, 0.f};
    for (int vc = 0; vc < 4; ++vc) {
        __syncthreads();
        for (int e = tid; e < 1024; e += 256) {
            int row = e >> 3, slot = e & 7;
            uint4 val = *(const uint4*)((const char*)vg + (size_t)row * 512 + vc * 128 + slot * 16);
            *(uint4*)(chunk + row * 128 + ((slot * 16) ^ ((row & 7) << 4))) = val;
        }
        __syncthreads();
        #pragma unroll
        for (int jc = 0; jc < 2; ++jc) {
            int prow = w * 16 + l15;
            int pcb = vc * 128 + jc * 64 + lhi * 16;
            bf16x8 ap = *(const bf16x8*)(lds + prow * 512 + (pcb ^ ((prow & 7) << 4)));
            #pragma unroll
            for (int ct = 0; ct < 8; ++ct) {
                int vrow = ct * 16 + l15;
                int vcb = jc * 64 + lhi * 16;
                bf16x8 bv = *(const bf16x8*)(chunk + vrow * 128 + (vcb ^ ((vrow & 7) << 4)));
                // swapped: D[c][tok] -> c contiguous per thread
                oacc[ct] = __builtin_amdgcn_mfma_f32_16x16x32_bf16(bv, ap, oacc[ct], 0, 0, 0);
            }
        }
    }
    bf16* og = ob + ((size_t)win * 256 + qbase) * 128;
    {
        int tok = w * 16 + l15;
        #pragma unroll
        for (int ct = 0; ct < 8; ++ct) {
            int c4 = ct * 16 + lhi * 4;
            union { bf16 h[4]; uint2 u; } t4;
            #pragma unroll
            for (int r = 0; r < 4; ++r) t4.h[r] = f2b(oacc[ct][r]);
            *(uint2*)(og + tok * 128 + c4) = t4.u;
        }
    }
}

// ---------------- K7: u = (o + PE(q)) * z, in place over o [win][tok][c] (elementwise) ----------------
__global__ __launch_bounds__(256) void k_peg(bf16* __restrict__ ob, const bf16* __restrict__ qb,
                                             const bf16* __restrict__ zb,
                                             const float* __restrict__ pew, const float* __restrict__ peb) {
    __shared__ float pw_lds[1152];
    __shared__ float pb_lds[128];
    int tid = threadIdx.x;
    for (int e = tid; e < 1152; e += 256) pw_lds[e] = pew[e];
    if (tid < 128) pb_lds[tid] = peb[tid];
    __syncthreads();
    int g = blockIdx.x * 256 + tid;          // 2,654,208 threads
    int c8 = g & 15, tok = (g >> 4) & 255, win = g >> 12;
    int cb = c8 * 8;
    int pp = tok >> 4, qq = tok & 15;
    size_t base = ((size_t)win * 256 + tok) * 128 + cb;
    float pv[8];
    #pragma unroll
    for (int cc = 0; cc < 8; ++cc) pv[cc] = pb_lds[cb + cc];
    #pragma unroll
    for (int ky = 0; ky < 3; ++ky) {
        int py = pp + ky - 1; if ((unsigned)py >= 16u) continue;
        #pragma unroll
        for (int kx = 0; kx < 3; ++kx) {
            int qx = qq + kx - 1; if ((unsigned)qx >= 16u) continue;
            union { uint4 u; bf16 h[8]; } qu;
            qu.u = *(const uint4*)(qb + ((size_t)win * 256 + py * 16 + qx) * 128 + cb);
            #pragma unroll
            for (int cc = 0; cc < 8; ++cc)
                pv[cc] += pw_lds[(cb + cc) * 9 + ky * 3 + kx] * b2f(qu.h[cc]);
        }
    }
    union { uint4 u; bf16 h[8]; } ou, zu, ru;
    ou.u = *(const uint4*)(ob + base);
    zu.u = *(const uint4*)(zb + base);
    #pragma unroll
    for (int cc = 0; cc < 8; ++cc)
        ru.h[cc] = f2b((b2f(ou.h[cc]) + pv[cc]) * b2f(zu.h[cc]));
    *(uint4*)(ob + base) = ru.u;
}

// ---------------- K8: proj MFMA GEMM + crop residual -> t2 [win][c][tok] ----------------
__global__ __launch_bounds__(256) void k_proj(const bf16* __restrict__ ub, const bf16* __restrict__ wt,
                                              const bf16* __restrict__ x1, bf16* __restrict__ t2) {
    __shared__ __align__(16) char lds[49152];   // [0,16K): u tile; [16K,48K): wt tile
    int tid = threadIdx.x;
    int lane = tid & 63, w = tid >> 6;
    int l15 = lane & 15, lhi = lane >> 4;
    int win = blockIdx.x >> 2, qbase = (blockIdx.x & 3) * 64;
    int b = win / 81; int r0 = win % 81; int top = (r0 / 9) * 14, left = (r0 % 9) * 14;
    const bf16* ug = ub + ((size_t)win * 256 + qbase) * 128;   // [64][128]
    char* wchunk = lds + 16384;
    for (int e = tid; e < 1024; e += 256) {
        int row = e >> 4, slot = e & 15;
        uint4 val = *(const uint4*)((const char*)ug + row * 256 + slot * 16);
        *(uint4*)(lds + row * 256 + ((slot * 16) ^ ((row & 7) << 4))) = val;
    }
    for (int e = tid; e < 2048; e += 256) {
        int row = e >> 4, slot = e & 15;
        uint4 val = *(const uint4*)((const char*)wt + row * 256 + slot * 16);
        *(uint4*)(wchunk + row * 256 + ((slot * 16) ^ ((row & 7) << 4))) = val;
    }
    __syncthreads();
    bf16x8 afr[4];
    {
        int row = w * 16 + l15;
        #pragma unroll
        for (int cc = 0; cc < 4; ++cc) {
            int cbyt = cc * 64 + lhi * 16;
            afr[cc] = *(const bf16x8*)(lds + row * 256 + (cbyt ^ ((row & 7) << 4)));
        }
    }
    f32x4 acc[8];
    #pragma unroll
    for (int t = 0; t < 8; ++t) acc[t] = (f32x4){0.f, 0.f, 0.f, 0.f};
    #pragma unroll
    for (int ot = 0; ot < 8; ++ot) {
        int row = ot * 16 + l15;
        #pragma unroll
        for (int cc = 0; cc < 4; ++cc) {
            int cbyt = cc * 64 + lhi * 16;
            bf16x8 bfr = *(const bf16x8*)(wchunk + row * 256 + (cbyt ^ ((row & 7) << 4)));
            acc[ot] = __builtin_amdgcn_mfma_f32_16x16x32_bf16(afr[cc], bfr, acc[ot], 0, 0, 0);
        }
    }
    int gtok0 = qbase + w * 16 + lhi * 4;
    int p = gtok0 >> 4, qq = gtok0 & 15;       // qq = lhi*4; qq+3 <= 15, row not crossed
    #pragma unroll
    for (int ot = 0; ot < 8; ++ot) {
        int o = ot * 16 + l15;
        const uint* xr32 = (const uint*)(x1 + (size_t)(b * C_ + o) * N_ + (top + p) * W_ + left + qq);
        union { uint u2[2]; bf16 h[4]; } xv;
        xv.u2[0] = xr32[0]; xv.u2[1] = xr32[1];
        union { bf16 h[4]; uint2 u; } t4;
        #pragma unroll
        for (int r = 0; r < 4; ++r) t4.h[r] = f2b(acc[ot][r] + b2f(xv.h[r]));
        *(uint2*)(t2 + (size_t)win * 32768 + (size_t)o * 256 + gtok0) = t4.u;
    }
}

// ---------------- K9: fused fold + LN2 + fc1 MFMA GEMM + gelu -> h1 (bf16), x2 (bf16) ----------------
__global__ __launch_bounds__(256) void k_fc1ln(const bf16* __restrict__ t2, const float* __restrict__ lng,
                                               const float* __restrict__ lnb, const bf16* __restrict__ wt1,
                                               const float* __restrict__ b1, bf16* __restrict__ h1,
                                               bf16* __restrict__ x2w) {
    __shared__ __align__(16) char lds[49664];   // [0,16K): A bf16 swizzled; [16K,...): xf fp32 [128][65] -> w chunk
    __shared__ float red2[8][64];
    __shared__ float mu_l[64], rs_l[64];
    int tid = threadIdx.x;
    int lane = tid & 63, w = tid >> 6;
    int l15 = lane & 15, lhi = lane >> 4;
    int gtok = blockIdx.x * 64; int b = gtok >> 14; int nb = gtok & (N_ - 1);
    int h = nb >> 7, w0 = nb & 127;
    int imin = (h < 16) ? 0 : (h - 2) / 14; int imax = h / 14; if (imax > 8) imax = 8;
    int jmin0 = (w0 < 16) ? 0 : (w0 - 2) / 14;
    int jmax0 = (w0 + 63) / 14; if (jmax0 > 8) jmax0 = 8;
    float* xf = (float*)(lds + 16384);
    char* wch = lds + 16384;
    for (int e = tid; e < 8320; e += 256) xf[e] = 0.f;
    __syncthreads();
    {
        int c = tid >> 1, half = tid & 1;
        for (int ii = imin; ii <= imax; ++ii) {
            int trow = h - ii * 14;
            for (int jj = jmin0; jj <= jmax0; ++jj) {
                int s = jj * 14 - w0 + half * 8;
                if (s >= 0 && s <= 56) {
                    const bf16* tp = t2 + (size_t)((b * 9 + ii) * 9 + jj) * 32768
                                   + (size_t)c * 256 + trow * 16 + half * 8;
                    union { uint4 u; bf16 hh[8]; } qv;
                    qv.u = *(const uint4*)tp;
                    float* xr = xf + c * 65 + s;
                    #pragma unroll
                    for (int k2 = 0; k2 < 8; ++k2) xr[k2] += b2f(qv.hh[k2]);
                }
            }
        }
    }
    __syncthreads();
    for (int e = tid; e < 2048; e += 256) {
        int c = e >> 4, qd = e & 15;
        int i0 = qd * 4;
        union { bf16 hh[4]; uint2 u; } t4;
        #pragma unroll
        for (int k2 = 0; k2 < 4; ++k2) {
            int i = i0 + k2;
            int wp = w0 + i;
            int jmn = (wp < 16) ? 0 : (wp - 2) / 14; int jmx = wp / 14; if (jmx > 8) jmx = 8;
            float inv = 1.0f / (float)((imax - imin + 1) * (jmx - jmn + 1));
            float val = xf[c * 65 + i] * inv;
            xf[c * 65 + i] = val;
            t4.hh[k2] = f2b(val);
        }
        *(uint2*)(x2w + (size_t)(b * C_ + c) * N_ + nb + i0) = t4.u;
    }
    __syncthreads();
    {
        int i = tid & 63, r = tid >> 6;
        float s = 0.f, ss = 0.f;
        for (int cc = r * 32; cc < r * 32 + 32; ++cc) { float vv = xf[cc * 65 + i]; s += vv; ss += vv * vv; }
        red2[r][i] = s; red2[4 + r][i] = ss;
    }
    __syncthreads();
    if (tid < 64) {
        float s = red2[0][tid] + red2[1][tid] + red2[2][tid] + red2[3][tid];
        float ss = red2[4][tid] + red2[5][tid] + red2[6][tid] + red2[7][tid];
        float mu = s * (1.f / 128.f); float var = ss * (1.f / 128.f) - mu * mu;
        mu_l[tid] = mu; rs_l[tid] = rsqrtf(var + 1e-6f);
    }
    __syncthreads();
    {
        int c = tid & 127;
        float g = lng[c], be = lnb[c];
        for (int e = tid; e < 8192; e += 256) {
            int i = e >> 7;
            float val = (xf[c * 65 + i] - mu_l[i]) * rs_l[i] * g + be;
            *(bf16*)(lds + i * 256 + ((2 * c) ^ ((i & 7) << 4))) = f2b(val);
        }
    }
    __syncthreads();
    bf16x8 afr[4];
    {
        int row = w * 16 + l15;
        #pragma unroll
        for (int cc = 0; cc < 4; ++cc) {
            int cbyt = cc * 64 + lhi * 16;
            afr[cc] = *(const bf16x8*)(lds + row * 256 + (cbyt ^ ((row & 7) << 4)));
        }
    }
    for (int p = 0; p < 2; ++p) {
        __syncthreads();
        for (int e = tid; e < 2048; e += 256) {
            int row = e >> 4, slot = e & 15;
            uint4 val = *(const uint4*)((const char*)wt1 + (size_t)(p * 128 + row) * 256 + slot * 16);
            *(uint4*)(wch + row * 256 + ((slot * 16) ^ ((row & 7) << 4))) = val;
        }
        __syncthreads();
        f32x4 acc[8];
        #pragma unroll
        for (int t = 0; t < 8; ++t) acc[t] = (f32x4){0.f, 0.f, 0.f, 0.f};
        #pragma unroll
        for (int ot = 0; ot < 8; ++ot) {
            int row = ot * 16 + l15;
            #pragma unroll
            for (int cc = 0; cc < 4; ++cc) {
                int cbyt = cc * 64 + lhi * 16;
                bf16x8 bfr = *(const bf16x8*)(wch + row * 256 + (cbyt ^ ((row & 7) << 4)));
                acc[ot] = __builtin_amdgcn_mfma_f32_16x16x32_bf16(afr[cc], bfr, acc[ot], 0, 0, 0);
            }
        }
        int n0 = nb + w * 16 + lhi * 4;
        #pragma unroll
        for (int ot = 0; ot < 8; ++ot) {
            int o = p * 128 + ot * 16 + l15;
            float bi = b1[o];
            union { bf16 h[4]; uint2 u; } t4;
            #pragma unroll
            for (int r = 0; r < 4; ++r) t4.h[r] = f2b(gelu_f(acc[ot][r] + bi));
            *(uint2*)(h1 + (size_t)(b * 256 + o) * N_ + n0) = t4.u;
        }
    }
}

// ---------------- K10: h2 = h1 + dwconv5x5(h1) + dw_b  full-plane LDS (bf16) ----------------
__global__ __launch_bounds__(256) void k_dw5p(const bf16* __restrict__ h1, const float* __restrict__ wdw,
                                              const float* __restrict__ bdw, bf16* __restrict__ h2) {
    __shared__ __align__(16) char tile[38016];     // 132 rows x 288B
    int tid = threadIdx.x;
    int bid = blockIdx.x;                          // 2048 = 8b * 256ch
    int ch = bid & 255, b = bid >> 8;
    const bf16* p = h1 + (size_t)(b * 256 + ch) * N_;
    for (int e = tid; e < 2376; e += 256) *(uint4*)(tile + e * 16) = (uint4){0, 0, 0, 0};
    __syncthreads();
    for (int e = tid; e < 2048; e += 256) {
        int gr = e >> 4, slot = e & 15;
        uint4 val = *(const uint4*)(p + gr * 128 + slot * 8);
        *(uint4*)(tile + (gr + 2) * 288 + 16 + slot * 16) = val;
    }
    float kw[25];
    #pragma unroll
    for (int j = 0; j < 25; ++j) kw[j] = wdw[ch * 25 + j];
    float bi = bdw[ch];
    __syncthreads();
    int hg = tid >> 4, wg = tid & 15;
    int h0 = hg * 8;
    float ring[5][12];
    #pragma unroll
    for (int j = 0; j < 4; ++j) load_row12(tile, h0 + j, wg, ring[j]);
    bf16* op = h2 + (size_t)(b * 256 + ch) * N_;
    #pragma unroll
    for (int rr = 0; rr < 8; ++rr) {
        load_row12(tile, h0 + rr + 4, wg, ring[(rr + 4) % 5]);
        float acc[8];
        #pragma unroll
        for (int ow = 0; ow < 8; ++ow) acc[ow] = bi;
        #pragma unroll
        for (int ky = 0; ky < 5; ++ky) {
            const float* e = ring[(rr + ky) % 5];
            #pragma unroll
            for (int ow = 0; ow < 8; ++ow) {
                #pragma unroll
                for (int kx = 0; kx < 5; ++kx)
                    acc[ow] = fmaf(kw[ky * 5 + kx], e[ow + kx], acc[ow]);
            }
        }
        {
            const float* e = ring[(rr + 2) % 5];
            #pragma unroll
            for (int ow = 0; ow < 8; ++ow) acc[ow] += e[ow + 2];
        }
        union { bf16 h[8]; uint4 u; } outv;
        #pragma unroll
        for (int ow = 0; ow < 8; ++ow) outv.h[ow] = f2b(acc[ow]);
        *(uint4*)(op + (h0 + rr) * 128 + wg * 8) = outv.u;
    }
}

// ---------------- K11: fc2 MFMA GEMM (K=256) + bias + residual -> d_out (fp32) ----------------
__global__ __launch_bounds__(256) void k_fc2_mfma(const bf16* __restrict__ h2, const bf16* __restrict__ wt2,
                                                  const float* __restrict__ b2, const bf16* __restrict__ x2,
                                                  float* __restrict__ out) {
    __shared__ __align__(16) char lds[65536];   // [0,32K): A tile [64][512B]; [32K,64K): W half
    int tid = threadIdx.x;
    int lane = tid & 63, w = tid >> 6;
    int l15 = lane & 15, lhi = lane >> 4;
    int gtok = blockIdx.x * 64; int b = gtok >> 14; int nb = gtok & (N_ - 1);
    char* wch = lds + 32768;
    for (int e = tid; e < 16384; e += 256) {
        int c = e >> 6, i = e & 63;
        bf16 val = h2[(size_t)(b * 256 + c) * N_ + nb + i];
        *(bf16*)(lds + i * 512 + ((2 * c) ^ ((i & 7) << 4))) = val;
    }
    __syncthreads();
    bf16x8 afr[8];
    {
        int row = w * 16 + l15;
        #pragma unroll
        for (int cc = 0; cc < 8; ++cc) {
            int cbyt = cc * 64 + lhi * 16;
            afr[cc] = *(const bf16x8*)(lds + row * 512 + (cbyt ^ ((row & 7) << 4)));
        }
    }
    f32x4 acc[8];
    #pragma unroll
    for (int t = 0; t < 8; ++t) acc[t] = (f32x4){0.f, 0.f, 0.f, 0.f};
    for (int kh = 0; kh < 2; ++kh) {
        __syncthreads();
        for (int e = tid; e < 2048; e += 256) {
            int row = e >> 4, slot = e & 15;
            uint4 val = *(const uint4*)((const char*)wt2 + (size_t)row * 512 + kh * 256 + slot * 16);
            *(uint4*)(wch + row * 256 + ((slot * 16) ^ ((row & 7) << 4))) = val;
        }
        __syncthreads();
        #pragma unroll
        for (int ot = 0; ot < 8; ++ot) {
            int row = ot * 16 + l15;
            #pragma unroll
            for (int cc = 0; cc < 4; ++cc) {
                int cbyt = cc * 64 + lhi * 16;
                bf16x8 bfr = *(const bf16x8*)(wch + row * 256 + (cbyt ^ ((row & 7) << 4)));
                acc[ot] = __builtin_amdgcn_mfma_f32_16x16x32_bf16(afr[kh * 4 + cc], bfr, acc[ot], 0, 0, 0);
            }
        }
    }
    int n0 = nb + w * 16 + lhi * 4;
    #pragma unroll
    for (int ot = 0; ot < 8; ++ot) {
        int o = ot * 16 + l15;
        size_t obase = (size_t)(b * C_ + o) * N_ + n0;
        float bi = b2[o];
        union { uint2 u; bf16 h[4]; } xr;
        xr.u = *(const uint2*)(x2 + obase);
        float4 r4;
        r4.x = acc[ot][0] + bi + b2f(xr.h[0]);
        r4.y = acc[ot][1] + bi + b2f(xr.h[1]);
        r4.z = acc[ot][2] + bi + b2f(xr.h[2]);
        r4.w = acc[ot][3] + bi + b2f(xr.h[3]);
        *(float4*)(out + obase) = r4;
    }
}

extern "C" void kernel_launch(void* const* d_in, const int* in_sizes, int n_in,
                              void* d_out, int out_size, void* d_ws, size_t ws_size,
                              hipStream_t stream) {
    const float* x         = (const float*)d_in[0];
    const float* lth_dw_w  = (const float*)d_in[2];
    const float* lth_pw_w  = (const float*)d_in[3];
    const float* lth_pw_b  = (const float*)d_in[4];
    const float* lth_gate_w= (const float*)d_in[5];
    const float* lth_gate_b= (const float*)d_in[6];
    const float* lth_scale = (const float*)d_in[7];
    const float* ln1_g     = (const float*)d_in[8];
    const float* ln1_b     = (const float*)d_in[9];
    const float* ln2_g     = (const float*)d_in[10];
    const float* ln2_b     = (const float*)d_in[11];
    const float* qkv_w     = (const float*)d_in[12];
    const float* gate_w    = (const float*)d_in[13];
    const float* gate_b    = (const float*)d_in[14];
    const float* proj_w    = (const float*)d_in[15];
    const float* pe_w      = (const float*)d_in[16];
    const float* pe_b      = (const float*)d_in[17];
    const float* fc1_w     = (const float*)d_in[18];
    const float* fc1_b     = (const float*)d_in[19];
    const float* dw_w      = (const float*)d_in[20];
    const float* dw_b      = (const float*)d_in[21];
    const float* fc2_w     = (const float*)d_in[22];
    const float* fc2_b     = (const float*)d_in[23];

    // Slab plan (bytes), peak ~234.5 MiB (proven R13):
    //  A: x1 ; h2 spans A+B (x1/o dead by dw5p)
    //  B: sg -> o -> u (k_peg in-place)
    //  C: q -> x2 (q dead after peg; x2 written by fc1ln)
    //  D: hf -> k -> t2 (t2 live through fc1ln)
    //  E: g -> v ; h1 spans E+F
    //  F: z
    //  G: wt(32K) H: wqkv(128K) I: wt1(64K) wt2(64K) wpw(32K)
    char* ws = (char*)d_ws;
    constexpr size_t SZ_X = 33554432;    // bf16, 16,777,216 elems
    constexpr size_t SZ_W = 42467328;    // bf16, 21,233,664 elems
    constexpr size_t OFF_A = 0;
    constexpr size_t OFF_B = OFF_A + SZ_X;
    constexpr size_t OFF_C = OFF_B + SZ_W;
    constexpr size_t OFF_D = OFF_C + SZ_W;
    constexpr size_t OFF_E = OFF_D + SZ_W;
    constexpr size_t OFF_F = OFF_E + SZ_W;
    constexpr size_t OFF_G = OFF_F + SZ_W;
    constexpr size_t OFF_H = OFF_G + 32768;
    constexpr size_t OFF_I = OFF_H + 131072;

    bf16*  x1  = (bf16*)(ws + OFF_A);
    bf16*  h2  = (bf16*)(ws + OFF_A);   // spans A+B
    float* sg  = (float*)(ws + OFF_B + 16777216);
    bf16*  o   = (bf16*)(ws + OFF_B);
    bf16*  q   = (bf16*)(ws + OFF_C);
    bf16*  x2  = (bf16*)(ws + OFF_C);
    bf16*  hf  = (bf16*)(ws + OFF_D);
    bf16*  k   = (bf16*)(ws + OFF_D);
    bf16*  t2  = (bf16*)(ws + OFF_D);
    bf16*  g   = (bf16*)(ws + OFF_E);
    bf16*  v   = (bf16*)(ws + OFF_E);
    bf16*  h1  = (bf16*)(ws + OFF_E);   // spans E+F
    bf16*  z   = (bf16*)(ws + OFF_F);
    bf16*  wt  = (bf16*)(ws + OFF_G);
    bf16*  wqkv= (bf16*)(ws + OFF_H);
    bf16*  wt1 = (bf16*)(ws + OFF_I);
    bf16*  wt2 = (bf16*)(ws + OFF_I + 65536);
    bf16*  wpw = (bf16*)(ws + OFF_I + 131072);

    k_wprep   <<<640,   256, 0, stream>>>(proj_w, qkv_w, gate_w, fc1_w, fc2_w, lth_pw_w,
                                          wt, wqkv, wt1, wt2, wpw);
    k_hf2     <<<8192,  256, 0, stream>>>(x, hf);
    k_sgate   <<<512,   256, 0, stream>>>(hf, lth_gate_w, lth_gate_b, sg);
    k_dw3p    <<<1024,  256, 0, stream>>>(hf, lth_dw_w, g);
    k_pw_mfma <<<2048,  256, 0, stream>>>(g, wpw, lth_pw_b, x, lth_scale, sg, x1);
    k_qkv_mfma<<<2592,  256, 0, stream>>>(x1, ln1_g, ln1_b, wqkv, gate_b, q, k, v, z);
    k_attn_mfma<<<2592, 256, 0, stream>>>(q, k, v, o);
    k_peg     <<<10368, 256, 0, stream>>>(o, q, z, pe_w, pe_b);
    k_proj    <<<2592,  256, 0, stream>>>(o, wt, x1, t2);
    k_fc1ln   <<<2048,  256, 0, stream>>>(t2, ln2_g, ln2_b, wt1, fc1_b, h1, x2);
    k_dw5p    <<<2048,  256, 0, stream>>>(h1, dw_w, dw_b, h2);
    k_fc2_mfma<<<2048,  256, 0, stream>>>(h2, wt2, fc2_b, x2, (float*)d_out);
}